// Round 10
// baseline (965.775 us; speedup 1.0000x reference)
//
#include <hip/hip_runtime.h>
#include <hip/hip_bf16.h>

#define D_IN 768
#define H_DIM 256
#define H_HALF 128
#define N_CLASSES 3

#define CAP1 256      // max |S1| (in-neighbors of claim; realistic max ~65)
#define CAP2 16384    // max |S2| (realistic ~1-4K)
#define CAPDEG 128    // max in-degree per target (realistic max ~65)
#define CAP0 1024     // claim bucket capacity
#define NBLK 1024     // persistent grid: 4 blocks/CU x 256 CU, guaranteed co-resident

typedef __attribute__((ext_vector_type(8))) short bf16x8;
typedef __attribute__((ext_vector_type(4))) float f32x4;

static __device__ __forceinline__ unsigned short f2bf(float f) {
    union { float f; unsigned u; } x; x.f = f;
    unsigned u = x.u;
    return (unsigned short)((u + 0x7FFFu + ((u >> 16) & 1u)) >> 16);  // RNE
}
static __device__ __forceinline__ float bf2f(unsigned short b) {
    union { unsigned u; float f; } x; x.u = ((unsigned)b) << 16;
    return x.f;
}
static __device__ __forceinline__ float bflo(unsigned v) {
    union { unsigned u; float f; } x; x.u = v << 16;
    return x.f;
}
static __device__ __forceinline__ float bfhi(unsigned v) {
    union { unsigned u; float f; } x; x.u = v & 0xFFFF0000u;
    return x.f;
}
static __device__ __forceinline__ bool bit_test(const unsigned* __restrict__ bm, int i) {
    return (bm[i >> 5] >> (i & 31)) & 1u;
}

// dedup-append node s to frontier list; set bits in bmCur and bmL
static __device__ __forceinline__ void try_append(int s, int* __restrict__ pos,
                                                  int* __restrict__ list, int* __restrict__ cnt,
                                                  unsigned* __restrict__ bmCur,
                                                  unsigned* __restrict__ bmL) {
    if (atomicCAS(&pos[s], -1, -2) == -1) {
        int i = atomicAdd(cnt, 1);
        list[i] = s;
        atomicOr(&bmCur[s >> 5], 1u << (s & 31));
        atomicOr(&bmL[s >> 5], 1u << (s & 31));
        atomicExch(&pos[s], i);
    }
}

// ---- manual grid barrier: generation-based, device-scope atomics + agent fence.
// Safe because grid (NBLK) <= guaranteed co-resident capacity (launch_bounds 256,4).
static __device__ __forceinline__ void grid_sync(int* barCnt, int* barGen) {
    __syncthreads();
    if (threadIdx.x == 0) {
        __threadfence();
        int g = atomicAdd(barGen, 0);
        if (atomicAdd(barCnt, 1) == (int)gridDim.x - 1) {
            atomicExch(barCnt, 0);
            atomicAdd(barGen, 1);
        } else {
            int guard = 0;
            while (atomicAdd(barGen, 0) == g) {
                if (++guard > (1 << 30)) break;   // hang-safety valve
                __builtin_amdgcn_s_sleep(8);
            }
        }
        __threadfence();
    }
    __syncthreads();
}

// ---- branchless scan phase: 4 match bits -> one coalesced byte store ----
static __device__ __forceinline__ void scan_phase(const int* __restrict__ dst,
                                                  const unsigned* __restrict__ bm,
                                                  unsigned char* __restrict__ mb,
                                                  int E, int tid, int nth) {
    int n4 = (E + 3) / 4;
    for (int idx = tid; idx < n4; idx += nth) {
        int e0 = idx * 4;
        unsigned m = 0;
        if (e0 + 4 <= E) {
            int4 d4 = *(const int4*)(dst + e0);
            m  = bit_test(bm, d4.x) ? 1u : 0u;
            m |= bit_test(bm, d4.y) ? 2u : 0u;
            m |= bit_test(bm, d4.z) ? 4u : 0u;
            m |= bit_test(bm, d4.w) ? 8u : 0u;
        } else {
            for (int e = e0; e < E; e++)
                if (bit_test(bm, dst[e])) m |= 1u << (e - e0);
        }
        mb[idx] = (unsigned char)m;
    }
}

// ---- fused extract+expand phase over match words ----
static __device__ __forceinline__ void xexpand_phase(const unsigned char* __restrict__ mb,
        int nbytes, const int* __restrict__ src, const int* __restrict__ dst,
        const int* __restrict__ posPrev, int* __restrict__ bucket, int* __restrict__ cur,
        int* __restrict__ posCur, int* __restrict__ listCur, int* __restrict__ cntCur,
        unsigned* __restrict__ bmCur, unsigned* __restrict__ bmL, int tid, int nth) {
    int nwords = (nbytes + 3) / 4;
    for (int i = tid; i < nwords; i += nth) {
        unsigned w = *(const unsigned*)(mb + (size_t)i * 4);
        int rem = nbytes - i * 4;
        if (rem < 4) w &= (1u << (rem * 8)) - 1u;
        while (w) {
            int b = __ffs(w) - 1;
            w &= w - 1;
            int e = (i * 4 + (b >> 3)) * 4 + (b & 7);
            int s = src[e], d = dst[e];
            int pt = posPrev[d];
            int p = atomicAdd(&cur[pt], 1);
            if (p < CAPDEG) bucket[(size_t)pt * CAPDEG + p] = s;
            try_append(s, posCur, listCur, cntCur, bmCur, bmL);
        }
    }
}

struct DiscArgs {
    const int* src; const int* dst; const int* claim;
    const float* W_in; const float* W_gnn;
    unsigned short* Wth_in; unsigned short* Wtl_in;
    unsigned short* Wth_g;  unsigned short* Wtl_g;
    int* B0; int* cnt;          // cnt[0]=c1 [1]=c2 [2]=c3 [3]=cur0 [4]=barCnt [5]=barGen
    int* pos1; int* pos2; int* pos3;
    int* list1; int* list2; int* list3;
    unsigned* bm1; unsigned* bm2; unsigned* bmL;
    int* cur1; int* cur2;
    int* B1; int* B2;
    unsigned char* mb;
    int* deg_out;
    int E;
};

// ---- ONE persistent kernel: weight split + pass1 | scan2 | xexpand2 | scan3 |
// xexpand3 | deg, separated by manual grid barriers ----
__global__ __launch_bounds__(256, 4) void k_discover(DiscArgs a) {
    const int tid = blockIdx.x * 256 + threadIdx.x;
    const int nth = gridDim.x * 256;
    const int E = a.E;
    const int n4 = (E + 3) / 4;
    int* barCnt = a.cnt + 4;
    int* barGen = a.cnt + 5;

    // ---- phase 1: weight split (independent) + pass1 (claim in-edges) ----
    {
        const int n1 = D_IN * H_DIM;
        const int ntot = n1 + 2 * H_DIM * H_DIM;
        for (int id = tid; id < ntot; id += nth) {
            if (id < n1) {
                int k = id >> 8, n = id & 255;
                float w = a.W_in[id];
                unsigned short h = f2bf(w);
                a.Wth_in[(size_t)n * D_IN + k] = h;
                a.Wtl_in[(size_t)n * D_IN + k] = f2bf(w - bf2f(h));
            } else {
                int t = id - n1;
                int l = t >> 16, r = t & 65535;
                int k = r >> 8, n = r & 255;
                float w = a.W_gnn[(size_t)l * 65536 + r];
                unsigned short h = f2bf(w);
                a.Wth_g[(size_t)l * 65536 + (size_t)n * H_DIM + k] = h;
                a.Wtl_g[(size_t)l * 65536 + (size_t)n * H_DIM + k] = f2bf(w - bf2f(h));
            }
        }
        const int c = a.claim[0];
        for (int idx = tid; idx < n4; idx += nth) {
            int e0 = idx * 4;
            if (e0 + 4 <= E) {
                int4 d4 = *(const int4*)(a.dst + e0);
#pragma unroll
                for (int k = 0; k < 4; k++) {
                    int d = (k == 0) ? d4.x : (k == 1) ? d4.y : (k == 2) ? d4.z : d4.w;
                    if (d == c) {
                        int s = a.src[e0 + k];
                        int p = atomicAdd(a.cnt + 3, 1);
                        if (p < CAP0) a.B0[p] = s;
                        try_append(s, a.pos1, a.list1, a.cnt, a.bm1, a.bmL);
                    }
                }
            } else {
                for (int e = e0; e < E; e++) {
                    if (a.dst[e] == c) {
                        int s = a.src[e];
                        int p = atomicAdd(a.cnt + 3, 1);
                        if (p < CAP0) a.B0[p] = s;
                        try_append(s, a.pos1, a.list1, a.cnt, a.bm1, a.bmL);
                    }
                }
            }
        }
    }
    grid_sync(barCnt, barGen);

    // ---- phase 2: scan dst vs bm1 ----
    scan_phase(a.dst, a.bm1, a.mb, E, tid, nth);
    grid_sync(barCnt, barGen);

    // ---- phase 3: expand level 2 (S1 targets -> B1; discover S2) ----
    xexpand_phase(a.mb, n4, a.src, a.dst, a.pos1, a.B1, a.cur1,
                  a.pos2, a.list2, a.cnt + 1, a.bm2, a.bmL, tid, nth);
    grid_sync(barCnt, barGen);

    // ---- phase 4: scan dst vs bm2 ----
    scan_phase(a.dst, a.bm2, a.mb, E, tid, nth);
    grid_sync(barCnt, barGen);

    // ---- phase 5: expand level 3 (S2 targets -> B2; discover S3) ----
    xexpand_phase(a.mb, n4, a.src, a.dst, a.pos2, a.B2, a.cur2,
                  a.pos3, a.list3, a.cnt + 2, a.bmL, a.bmL, tid, nth);
    grid_sync(barCnt, barGen);

    // ---- phase 6: out-degrees of live nodes ----
    for (int idx = tid; idx < n4; idx += nth) {
        int e0 = idx * 4;
        if (e0 + 4 <= E) {
            int4 s4 = *(const int4*)(a.src + e0);
#pragma unroll
            for (int k = 0; k < 4; k++) {
                int s = (k == 0) ? s4.x : (k == 1) ? s4.y : (k == 2) ? s4.z : s4.w;
                if (bit_test(a.bmL, s)) atomicAdd(&a.deg_out[s], 1);
            }
        } else {
            for (int e = e0; e < E; e++) {
                int s = a.src[e];
                if (bit_test(a.bmL, s)) atomicAdd(&a.deg_out[s], 1);
            }
        }
    }
}

// ---- split-precision MFMA GEMM over compact frontier rows ----
// Passes: Ah*Bh always; + Al*Bh if ALO; + Ah*Bl if BLO.
// Msg[row][256] = (relu?)(acc+bias) * rsqrt(deg_out[rowmap[row]])  (bf16)
template<bool GATHER_A, bool RELU, bool ALO, bool BLO>
__global__ __launch_bounds__(256) void k_mfma_gemm(
    const float* __restrict__ A, const int* __restrict__ rowmap,
    const int* __restrict__ Mptr,
    const unsigned short* __restrict__ Bth, const unsigned short* __restrict__ Btl,
    const float* __restrict__ bias, const int* __restrict__ deg_out,
    unsigned short* __restrict__ MsgOut, int K) {
    int M = Mptr[0];
    int row0 = blockIdx.x * 128;
    if (row0 >= M) return;
    int col0 = blockIdx.y * 128;

    __shared__ unsigned short Ash[128][40];
    __shared__ unsigned short Asl[ALO ? 128 : 1][40];
    __shared__ unsigned short Bsh[128][40];
    __shared__ unsigned short Bsl[BLO ? 128 : 1][40];

    int tid = threadIdx.x;
    int lane = tid & 63;
    int wv = tid >> 6;
    int wr = wv >> 1, wc = wv & 1;

    f32x4 acc[4][4];
#pragma unroll
    for (int mi = 0; mi < 4; mi++)
#pragma unroll
        for (int ni = 0; ni < 4; ni++) acc[mi][ni] = (f32x4){0.f, 0.f, 0.f, 0.f};

    int kf = (lane >> 4) * 8;
    int rsel = lane & 15;

    for (int kk = 0; kk < K; kk += 32) {
#pragma unroll
        for (int u = 0; u < 4; u++) {
            int i = tid + u * 256;
            int r = i >> 3;
            int c4 = (i & 7) * 4;
            float4 v = {0.f, 0.f, 0.f, 0.f};
            int row = row0 + r;
            if (row < M) {
                int arow = GATHER_A ? rowmap[row] : row;
                v = *(const float4*)(A + (size_t)arow * K + kk + c4);
            }
            ushort4 h;
            h.x = f2bf(v.x); h.y = f2bf(v.y); h.z = f2bf(v.z); h.w = f2bf(v.w);
            *(ushort4*)&Ash[r][c4] = h;
            if (ALO) {
                ushort4 l;
                l.x = f2bf(v.x - bf2f(h.x));
                l.y = f2bf(v.y - bf2f(h.y));
                l.z = f2bf(v.z - bf2f(h.z));
                l.w = f2bf(v.w - bf2f(h.w));
                *(ushort4*)&Asl[r][c4] = l;
            }
        }
#pragma unroll
        for (int u = 0; u < 2; u++) {
            int i = tid + u * 256;
            int r = i >> 2;
            int c8 = (i & 3) * 8;
            *(uint4*)&Bsh[r][c8] = *(const uint4*)(Bth + (size_t)(col0 + r) * K + kk + c8);
            if (BLO)
                *(uint4*)&Bsl[r][c8] = *(const uint4*)(Btl + (size_t)(col0 + r) * K + kk + c8);
        }
        __syncthreads();

        bf16x8 ah[4], al[4], bh[4], bl[4];
#pragma unroll
        for (int mi = 0; mi < 4; mi++) {
            ah[mi] = *(const bf16x8*)&Ash[wr * 64 + mi * 16 + rsel][kf];
            if (ALO) al[mi] = *(const bf16x8*)&Asl[wr * 64 + mi * 16 + rsel][kf];
        }
#pragma unroll
        for (int ni = 0; ni < 4; ni++) {
            bh[ni] = *(const bf16x8*)&Bsh[wc * 64 + ni * 16 + rsel][kf];
            if (BLO) bl[ni] = *(const bf16x8*)&Bsl[wc * 64 + ni * 16 + rsel][kf];
        }
#pragma unroll
        for (int mi = 0; mi < 4; mi++)
#pragma unroll
            for (int ni = 0; ni < 4; ni++) {
                acc[mi][ni] = __builtin_amdgcn_mfma_f32_16x16x32_bf16(ah[mi], bh[ni], acc[mi][ni], 0, 0, 0);
                if (ALO)
                    acc[mi][ni] = __builtin_amdgcn_mfma_f32_16x16x32_bf16(al[mi], bh[ni], acc[mi][ni], 0, 0, 0);
                if (BLO)
                    acc[mi][ni] = __builtin_amdgcn_mfma_f32_16x16x32_bf16(ah[mi], bl[ni], acc[mi][ni], 0, 0, 0);
            }
        __syncthreads();
    }

    int lr = (lane >> 4) * 4;
    int lc = lane & 15;
    float bcol[4];
#pragma unroll
    for (int ni = 0; ni < 4; ni++) bcol[ni] = bias[col0 + wc * 64 + ni * 16 + lc];

#pragma unroll
    for (int mi = 0; mi < 4; mi++) {
#pragma unroll
        for (int r = 0; r < 4; r++) {
            int row = row0 + wr * 64 + mi * 16 + lr + r;
            if (row >= M) continue;
            float ns = rsqrtf((float)max(deg_out[rowmap[row]], 1));
#pragma unroll
            for (int ni = 0; ni < 4; ni++) {
                int col = col0 + wc * 64 + ni * 16 + lc;
                float v = acc[mi][ni][r] + bcol[ni];
                if (RELU) v = fmaxf(v, 0.f);
                MsgOut[(size_t)row * 256 + col] = f2bf(v * ns);
            }
        }
    }
}

// ---- bucket aggregation: one wave per target; norm_dst from bucket cursor ----
__global__ void k_gather_agg(const int* __restrict__ nTptr, const int* __restrict__ bucket,
                             const int* __restrict__ cur, const int* __restrict__ posSrc,
                             const uint2* __restrict__ Msg, float4* __restrict__ Agg) {
    int nT = nTptr[0];
    int gt = blockIdx.x * blockDim.x + threadIdx.x;
    int w = gt >> 6, lane = gt & 63;
    if (w >= nT) return;
    int deg = cur[w];
    int ne = min(deg, CAPDEG);
    const int* bk = bucket + (size_t)w * CAPDEG;
    float a0 = 0.f, a1 = 0.f, a2 = 0.f, a3 = 0.f;
    int e = 0;
    for (; e + 1 < ne; e += 2) {
        int s0 = __builtin_amdgcn_readfirstlane(bk[e]);
        int s1 = __builtin_amdgcn_readfirstlane(bk[e + 1]);
        int i0 = __builtin_amdgcn_readfirstlane(posSrc[s0]);
        int i1 = __builtin_amdgcn_readfirstlane(posSrc[s1]);
        uint2 v0 = Msg[(size_t)i0 * 64 + lane];
        uint2 v1 = Msg[(size_t)i1 * 64 + lane];
        a0 += bflo(v0.x) + bflo(v1.x);
        a1 += bfhi(v0.x) + bfhi(v1.x);
        a2 += bflo(v0.y) + bflo(v1.y);
        a3 += bfhi(v0.y) + bfhi(v1.y);
    }
    for (; e < ne; e++) {
        int s = __builtin_amdgcn_readfirstlane(bk[e]);
        int i0 = __builtin_amdgcn_readfirstlane(posSrc[s]);
        uint2 v = Msg[(size_t)i0 * 64 + lane];
        a0 += bflo(v.x); a1 += bfhi(v.x); a2 += bflo(v.y); a3 += bfhi(v.y);
    }
    float nd = rsqrtf((float)max(deg, 1));
    float4 o;
    o.x = a0 * nd; o.y = a1 * nd; o.z = a2 * nd; o.w = a3 * nd;
    Agg[(size_t)w * 64 + lane] = o;
}

// ---- final: claim aggregation (bucket B0) + layer-3 GEMV + classifier head ----
__global__ void k_final(const int* __restrict__ B0, const int* __restrict__ cur0,
                        const int* __restrict__ pos1, const unsigned short* __restrict__ Msg2,
                        const float* __restrict__ W3, const float* __restrict__ b3,
                        const float* __restrict__ Wc1, const float* __restrict__ bc1,
                        const float* __restrict__ Wc2, const float* __restrict__ bc2,
                        float* __restrict__ out) {
    __shared__ float agg[H_DIM];
    __shared__ float h3[H_DIM];
    __shared__ float hid[H_HALF];
    int t = threadIdx.x;
    int deg = cur0[0];
    int ne = min(deg, CAP0);
    float a = 0.f;
    for (int e = 0; e < ne; e++) {
        int s = B0[e];
        int idx = pos1[s];
        a += bf2f(Msg2[(size_t)idx * H_DIM + t]);
    }
    agg[t] = a * rsqrtf((float)max(deg, 1));
    __syncthreads();
    float acc = b3[t];
    for (int k = 0; k < H_DIM; k++) acc += agg[k] * W3[k * H_DIM + t];
    h3[t] = fmaxf(acc, 0.f);
    __syncthreads();
    if (t < H_HALF) {
        float x = bc1[t];
        for (int k = 0; k < H_DIM; k++) x += h3[k] * Wc1[k * H_HALF + t];
        hid[t] = fmaxf(x, 0.f);
    }
    __syncthreads();
    if (t < N_CLASSES) {
        float x = bc2[t];
        for (int j = 0; j < H_HALF; j++) x += hid[j] * Wc2[j * N_CLASSES + t];
        out[t] = x;
    }
}

extern "C" void kernel_launch(void* const* d_in, const int* in_sizes, int n_in,
                              void* d_out, int out_size, void* d_ws, size_t ws_size,
                              hipStream_t stream) {
    const float* nf    = (const float*)d_in[0];
    const int*   esrc  = (const int*)d_in[1];
    const int*   edst  = (const int*)d_in[2];
    const int*   claim = (const int*)d_in[3];
    const float* W_in  = (const float*)d_in[4];
    const float* b_in  = (const float*)d_in[5];
    const float* W_gnn = (const float*)d_in[6];
    const float* b_gnn = (const float*)d_in[7];
    const float* Wc1   = (const float*)d_in[8];
    const float* bc1   = (const float*)d_in[9];
    const float* Wc2   = (const float*)d_in[10];
    const float* bc2   = (const float*)d_in[11];

    const int N = in_sizes[0] / D_IN;
    const int E = in_sizes[1];
    const int BMWP = (((N + 31) / 32) + 63) & ~63;   // bitmap words, 256B-aligned stride
    const int NBYTES = (E + 3) / 4;                  // match-byte array length

    char* p = (char*)d_ws;
    auto alloc = [&](size_t bytes) -> void* {
        void* r = (void*)p;
        p += (bytes + 255) & ~(size_t)255;
        return r;
    };
    // ---- zero region (single memset) ----
    char* zero0 = p;
    int* deg_out  = (int*)alloc((size_t)N * 4);
    unsigned* bms = (unsigned*)alloc((size_t)3 * BMWP * 4);  // bm1 | bm2 | bmL
    int* cnt      = (int*)alloc(8 * 4);      // [c1, c2, c3, cur0, barCnt, barGen]
    int* cur1     = (int*)alloc((size_t)CAP1 * 4);
    int* cur2     = (int*)alloc((size_t)CAP2 * 4);
    size_t zeroBytes = (size_t)(p - zero0);
    // ---- 0xFF region (single memset) ----
    char* ff0 = p;
    int* pos1     = (int*)alloc((size_t)N * 4);
    int* pos2     = (int*)alloc((size_t)N * 4);
    int* pos3     = (int*)alloc((size_t)N * 4);
    size_t ffBytes = (size_t)(p - ff0);
    // ---- uninitialized ----
    unsigned* bm1 = bms;
    unsigned* bm2 = bms + BMWP;
    unsigned* bmL = bms + 2 * BMWP;
    int* list1    = (int*)alloc((size_t)CAP1 * 4);
    int* list2    = (int*)alloc((size_t)CAP2 * 4);
    int* list3    = (int*)alloc((size_t)N * 4);
    int* B0       = (int*)alloc((size_t)CAP0 * 4);
    int* B1       = (int*)alloc((size_t)CAP1 * CAPDEG * 4);
    int* B2       = (int*)alloc((size_t)CAP2 * CAPDEG * 4);
    unsigned char* mb = (unsigned char*)alloc((size_t)NBYTES + 8);
    unsigned short* Wth_in = (unsigned short*)alloc((size_t)D_IN * H_DIM * 2);
    unsigned short* Wtl_in = (unsigned short*)alloc((size_t)D_IN * H_DIM * 2);
    unsigned short* Wth_g  = (unsigned short*)alloc((size_t)2 * H_DIM * H_DIM * 2);
    unsigned short* Wtl_g  = (unsigned short*)alloc((size_t)2 * H_DIM * H_DIM * 2);
    unsigned short* Msg0 = (unsigned short*)alloc((size_t)N * H_DIM * 2);
    unsigned short* Msg1 = (unsigned short*)alloc((size_t)CAP2 * H_DIM * 2);
    unsigned short* Msg2 = (unsigned short*)alloc((size_t)CAP1 * H_DIM * 2);
    float* Agg1 = (float*)alloc((size_t)CAP2 * H_DIM * 4);
    float* Agg2 = (float*)alloc((size_t)CAP1 * H_DIM * 4);

    hipMemsetAsync(zero0, 0, zeroBytes, stream);
    hipMemsetAsync(ff0, 0xFF, ffBytes, stream);

    // ---- fused discovery: wt_split + pass1 | scan2 | xexpand2 | scan3 | xexpand3 | deg
    DiscArgs da;
    da.src = esrc; da.dst = edst; da.claim = claim;
    da.W_in = W_in; da.W_gnn = W_gnn;
    da.Wth_in = Wth_in; da.Wtl_in = Wtl_in; da.Wth_g = Wth_g; da.Wtl_g = Wtl_g;
    da.B0 = B0; da.cnt = cnt;
    da.pos1 = pos1; da.pos2 = pos2; da.pos3 = pos3;
    da.list1 = list1; da.list2 = list2; da.list3 = list3;
    da.bm1 = bm1; da.bm2 = bm2; da.bmL = bmL;
    da.cur1 = cur1; da.cur2 = cur2;
    da.B1 = B1; da.B2 = B2;
    da.mb = mb; da.deg_out = deg_out;
    da.E = E;
    k_discover<<<NBLK, 256, 0, stream>>>(da);

    // projection on S3 (single-pass bf16): Msg0[i] = (nf[list3[i]]@W_in + b_in)*rsqrt(deg)
    dim3 gproj((N + 127) / 128, 2);
    k_mfma_gemm<true, false, false, false><<<gproj, 256, 0, stream>>>(
        nf, list3, cnt + 2, Wth_in, Wtl_in, b_in, deg_out, Msg0, D_IN);

    // layer 1: aggregate S2 targets from Msg0, then GEMM (full split)
    k_gather_agg<<<(CAP2 * 64 + 255) / 256, 256, 0, stream>>>(cnt + 1, B2, cur2, pos3,
                                                              (const uint2*)Msg0, (float4*)Agg1);
    dim3 g1(CAP2 / 128, 2);
    k_mfma_gemm<false, true, true, true><<<g1, 256, 0, stream>>>(
        Agg1, list2, cnt + 1, Wth_g, Wtl_g, b_gnn, deg_out, Msg1, H_DIM);

    // layer 2: aggregate S1 targets from Msg1, then GEMM (full split)
    k_gather_agg<<<(CAP1 * 64 + 255) / 256, 256, 0, stream>>>(cnt, B1, cur1, pos2,
                                                              (const uint2*)Msg1, (float4*)Agg2);
    dim3 g2(CAP1 / 128, 2);
    k_mfma_gemm<false, true, true, true><<<g2, 256, 0, stream>>>(
        Agg2, list1, cnt, Wth_g + (size_t)H_DIM * H_DIM, Wtl_g + (size_t)H_DIM * H_DIM,
        b_gnn + H_DIM, deg_out, Msg2, H_DIM);

    // layer 3 (claim only) + classifier head
    k_final<<<1, H_DIM, 0, stream>>>(B0, cnt + 3, pos1, Msg2,
                                     W_gnn + (size_t)2 * H_DIM * H_DIM, b_gnn + 2 * H_DIM,
                                     Wc1, bc1, Wc2, bc2, (float*)d_out);
}

// Round 11
// 338.635 us; speedup vs baseline: 2.8520x; 2.8520x over previous
//
#include <hip/hip_runtime.h>
#include <hip/hip_bf16.h>

#define D_IN 768
#define H_DIM 256
#define H_HALF 128
#define N_CLASSES 3

#define CAP1 256      // max |S1| (in-neighbors of claim; realistic max ~65)
#define CAP2 16384    // max |S2| (realistic ~1-4K)
#define CAPDEG 128    // max in-degree per target (realistic max ~65)
#define CAP0 1024     // claim bucket capacity

typedef __attribute__((ext_vector_type(8))) short bf16x8;
typedef __attribute__((ext_vector_type(4))) float f32x4;

static __device__ __forceinline__ unsigned short f2bf(float f) {
    union { float f; unsigned u; } x; x.f = f;
    unsigned u = x.u;
    return (unsigned short)((u + 0x7FFFu + ((u >> 16) & 1u)) >> 16);  // RNE
}
static __device__ __forceinline__ float bf2f(unsigned short b) {
    union { unsigned u; float f; } x; x.u = ((unsigned)b) << 16;
    return x.f;
}
static __device__ __forceinline__ float bflo(unsigned v) {
    union { unsigned u; float f; } x; x.u = v << 16;
    return x.f;
}
static __device__ __forceinline__ float bfhi(unsigned v) {
    union { unsigned u; float f; } x; x.u = v & 0xFFFF0000u;
    return x.f;
}
static __device__ __forceinline__ bool bit_test(const unsigned* __restrict__ bm, int i) {
    return (bm[i >> 5] >> (i & 31)) & 1u;
}

// dedup-append node s to frontier list; set bits in bmCur and bmL
static __device__ __forceinline__ void try_append(int s, int* __restrict__ pos,
                                                  int* __restrict__ list, int* __restrict__ cnt,
                                                  unsigned* __restrict__ bmCur,
                                                  unsigned* __restrict__ bmL) {
    if (atomicCAS(&pos[s], -1, -2) == -1) {
        int i = atomicAdd(cnt, 1);
        list[i] = s;
        atomicOr(&bmCur[s >> 5], 1u << (s & 31));
        atomicOr(&bmL[s >> 5], 1u << (s & 31));
        atomicExch(&pos[s], i);
    }
}

// ---- pass 1 (+ fused weight split): edges into claim -> B0; srcs -> S1 ----
__global__ void k_pass1(const int* __restrict__ src, const int* __restrict__ dst,
                        const int* __restrict__ claim, int* __restrict__ B0,
                        int* __restrict__ cur0, int* __restrict__ pos1,
                        int* __restrict__ list1, int* __restrict__ cnt1,
                        unsigned* __restrict__ bm1, unsigned* __restrict__ bmL,
                        const float* __restrict__ W_in, const float* __restrict__ W_gnn,
                        unsigned short* __restrict__ Wth_in, unsigned short* __restrict__ Wtl_in,
                        unsigned short* __restrict__ Wth_g, unsigned short* __restrict__ Wtl_g,
                        int E) {
    int idx = blockIdx.x * 256 + threadIdx.x;
    int nth = gridDim.x * 256;
    // fused weight convert+transpose+split (independent of edge work)
    {
        const int n1 = D_IN * H_DIM;
        const int ntot = n1 + 2 * H_DIM * H_DIM;
        for (int id = idx; id < ntot; id += nth) {
            if (id < n1) {
                int k = id >> 8, n = id & 255;
                float w = W_in[id];
                unsigned short h = f2bf(w);
                Wth_in[(size_t)n * D_IN + k] = h;
                Wtl_in[(size_t)n * D_IN + k] = f2bf(w - bf2f(h));
            } else {
                int t = id - n1;
                int l = t >> 16, r = t & 65535;
                int k = r >> 8, n = r & 255;
                float w = W_gnn[(size_t)l * 65536 + r];
                unsigned short h = f2bf(w);
                Wth_g[(size_t)l * 65536 + (size_t)n * H_DIM + k] = h;
                Wtl_g[(size_t)l * 65536 + (size_t)n * H_DIM + k] = f2bf(w - bf2f(h));
            }
        }
    }
    int c = claim[0];
    int e0 = idx * 4;
    if (e0 >= E) return;
    if (e0 + 4 <= E) {
        int4 d4 = *(const int4*)(dst + e0);
#pragma unroll
        for (int k = 0; k < 4; k++) {
            int d = (k == 0) ? d4.x : (k == 1) ? d4.y : (k == 2) ? d4.z : d4.w;
            if (d == c) {
                int s = src[e0 + k];
                int p = atomicAdd(cur0, 1);
                if (p < CAP0) B0[p] = s;
                try_append(s, pos1, list1, cnt1, bm1, bmL);
            }
        }
    } else {
        for (int e = e0; e < E; e++) {
            int d = dst[e];
            if (d == c) {
                int s = src[e];
                int p = atomicAdd(cur0, 1);
                if (p < CAP0) B0[p] = s;
                try_append(s, pos1, list1, cnt1, bm1, bmL);
            }
        }
    }
}

// ---- BRANCHLESS scan: 4 match bits -> one unconditional coalesced byte store ----
__global__ void k_scan_bm(const int* __restrict__ dst, const unsigned* __restrict__ bmPrev,
                          unsigned char* __restrict__ mb, int E) {
    int idx = blockIdx.x * 256 + threadIdx.x;
    int e0 = idx * 4;
    if (e0 >= E) return;
    unsigned m = 0;
    if (e0 + 4 <= E) {
        int4 d4 = *(const int4*)(dst + e0);
        m  = bit_test(bmPrev, d4.x) ? 1u : 0u;
        m |= bit_test(bmPrev, d4.y) ? 2u : 0u;
        m |= bit_test(bmPrev, d4.z) ? 4u : 0u;
        m |= bit_test(bmPrev, d4.w) ? 8u : 0u;
    } else {
        for (int e = e0; e < E; e++)
            if (bit_test(bmPrev, dst[e])) m |= 1u << (e - e0);
    }
    mb[idx] = (unsigned char)m;
}

// ---- fused extract+expand: scan match bytes (E/16 words), expand set bits ----
__global__ void k_xexpand(const unsigned char* __restrict__ mb, int nbytes,
                          const int* __restrict__ src, const int* __restrict__ dst,
                          const int* __restrict__ posPrev, int* __restrict__ bucket,
                          int* __restrict__ cur, int* __restrict__ posCur,
                          int* __restrict__ listCur, int* __restrict__ cntCur,
                          unsigned* __restrict__ bmCur, unsigned* __restrict__ bmL) {
    int i = blockIdx.x * 256 + threadIdx.x;   // word index
    int nwords = (nbytes + 3) / 4;
    if (i >= nwords) return;
    unsigned w = *(const unsigned*)(mb + (size_t)i * 4);  // +8B alloc pad makes this safe
    int rem = nbytes - i * 4;
    if (rem < 4) w &= (1u << (rem * 8)) - 1u;
    if (!w) return;
    while (w) {
        int b = __ffs(w) - 1;
        w &= w - 1;
        int e = (i * 4 + (b >> 3)) * 4 + (b & 7);
        int s = src[e], d = dst[e];
        int pt = posPrev[d];
        int p = atomicAdd(&cur[pt], 1);
        if (p < CAPDEG) bucket[(size_t)pt * CAPDEG + p] = s;
        try_append(s, posCur, listCur, cntCur, bmCur, bmL);
    }
}

// ---- out-degrees for live nodes (predicated void atomics; proven fast) ----
__global__ void k_deg(const int* __restrict__ src, const unsigned* __restrict__ bmL,
                      int* __restrict__ deg_out, int E) {
    int idx = blockIdx.x * 256 + threadIdx.x;
    int e0 = idx * 4;
    if (e0 >= E) return;
    if (e0 + 4 <= E) {
        int4 s4 = *(const int4*)(src + e0);
#pragma unroll
        for (int k = 0; k < 4; k++) {
            int s = (k == 0) ? s4.x : (k == 1) ? s4.y : (k == 2) ? s4.z : s4.w;
            if (bit_test(bmL, s)) atomicAdd(&deg_out[s], 1);
        }
    } else {
        for (int e = e0; e < E; e++) {
            int s = src[e];
            if (bit_test(bmL, s)) atomicAdd(&deg_out[s], 1);
        }
    }
}

// ---- split-precision MFMA GEMM over compact frontier rows ----
// Passes: Ah*Bh always; + Al*Bh if ALO; + Ah*Bl if BLO.
// Msg[row][256] = (relu?)(acc+bias) * rsqrt(deg_out[rowmap[row]])  (bf16)
template<bool GATHER_A, bool RELU, bool ALO, bool BLO>
__global__ __launch_bounds__(256) void k_mfma_gemm(
    const float* __restrict__ A, const int* __restrict__ rowmap,
    const int* __restrict__ Mptr,
    const unsigned short* __restrict__ Bth, const unsigned short* __restrict__ Btl,
    const float* __restrict__ bias, const int* __restrict__ deg_out,
    unsigned short* __restrict__ MsgOut, int K) {
    int M = Mptr[0];
    int row0 = blockIdx.x * 128;
    if (row0 >= M) return;
    int col0 = blockIdx.y * 128;

    __shared__ unsigned short Ash[128][40];
    __shared__ unsigned short Asl[ALO ? 128 : 1][40];
    __shared__ unsigned short Bsh[128][40];
    __shared__ unsigned short Bsl[BLO ? 128 : 1][40];

    int tid = threadIdx.x;
    int lane = tid & 63;
    int wv = tid >> 6;
    int wr = wv >> 1, wc = wv & 1;

    f32x4 acc[4][4];
#pragma unroll
    for (int mi = 0; mi < 4; mi++)
#pragma unroll
        for (int ni = 0; ni < 4; ni++) acc[mi][ni] = (f32x4){0.f, 0.f, 0.f, 0.f};

    int kf = (lane >> 4) * 8;
    int rsel = lane & 15;

    for (int kk = 0; kk < K; kk += 32) {
#pragma unroll
        for (int u = 0; u < 4; u++) {
            int i = tid + u * 256;
            int r = i >> 3;
            int c4 = (i & 7) * 4;
            float4 v = {0.f, 0.f, 0.f, 0.f};
            int row = row0 + r;
            if (row < M) {
                int arow = GATHER_A ? rowmap[row] : row;
                v = *(const float4*)(A + (size_t)arow * K + kk + c4);
            }
            ushort4 h;
            h.x = f2bf(v.x); h.y = f2bf(v.y); h.z = f2bf(v.z); h.w = f2bf(v.w);
            *(ushort4*)&Ash[r][c4] = h;
            if (ALO) {
                ushort4 l;
                l.x = f2bf(v.x - bf2f(h.x));
                l.y = f2bf(v.y - bf2f(h.y));
                l.z = f2bf(v.z - bf2f(h.z));
                l.w = f2bf(v.w - bf2f(h.w));
                *(ushort4*)&Asl[r][c4] = l;
            }
        }
#pragma unroll
        for (int u = 0; u < 2; u++) {
            int i = tid + u * 256;
            int r = i >> 2;
            int c8 = (i & 3) * 8;
            *(uint4*)&Bsh[r][c8] = *(const uint4*)(Bth + (size_t)(col0 + r) * K + kk + c8);
            if (BLO)
                *(uint4*)&Bsl[r][c8] = *(const uint4*)(Btl + (size_t)(col0 + r) * K + kk + c8);
        }
        __syncthreads();

        bf16x8 ah[4], al[4], bh[4], bl[4];
#pragma unroll
        for (int mi = 0; mi < 4; mi++) {
            ah[mi] = *(const bf16x8*)&Ash[wr * 64 + mi * 16 + rsel][kf];
            if (ALO) al[mi] = *(const bf16x8*)&Asl[wr * 64 + mi * 16 + rsel][kf];
        }
#pragma unroll
        for (int ni = 0; ni < 4; ni++) {
            bh[ni] = *(const bf16x8*)&Bsh[wc * 64 + ni * 16 + rsel][kf];
            if (BLO) bl[ni] = *(const bf16x8*)&Bsl[wc * 64 + ni * 16 + rsel][kf];
        }
#pragma unroll
        for (int mi = 0; mi < 4; mi++)
#pragma unroll
            for (int ni = 0; ni < 4; ni++) {
                acc[mi][ni] = __builtin_amdgcn_mfma_f32_16x16x32_bf16(ah[mi], bh[ni], acc[mi][ni], 0, 0, 0);
                if (ALO)
                    acc[mi][ni] = __builtin_amdgcn_mfma_f32_16x16x32_bf16(al[mi], bh[ni], acc[mi][ni], 0, 0, 0);
                if (BLO)
                    acc[mi][ni] = __builtin_amdgcn_mfma_f32_16x16x32_bf16(ah[mi], bl[ni], acc[mi][ni], 0, 0, 0);
            }
        __syncthreads();
    }

    int lr = (lane >> 4) * 4;
    int lc = lane & 15;
    float bcol[4];
#pragma unroll
    for (int ni = 0; ni < 4; ni++) bcol[ni] = bias[col0 + wc * 64 + ni * 16 + lc];

#pragma unroll
    for (int mi = 0; mi < 4; mi++) {
#pragma unroll
        for (int r = 0; r < 4; r++) {
            int row = row0 + wr * 64 + mi * 16 + lr + r;
            if (row >= M) continue;
            float ns = rsqrtf((float)max(deg_out[rowmap[row]], 1));
#pragma unroll
            for (int ni = 0; ni < 4; ni++) {
                int col = col0 + wc * 64 + ni * 16 + lc;
                float v = acc[mi][ni][r] + bcol[ni];
                if (RELU) v = fmaxf(v, 0.f);
                MsgOut[(size_t)row * 256 + col] = f2bf(v * ns);
            }
        }
    }
}

// ---- bucket aggregation: one wave per target; norm_dst from bucket cursor ----
__global__ void k_gather_agg(const int* __restrict__ nTptr, const int* __restrict__ bucket,
                             const int* __restrict__ cur, const int* __restrict__ posSrc,
                             const uint2* __restrict__ Msg, float4* __restrict__ Agg) {
    int nT = nTptr[0];
    int gt = blockIdx.x * blockDim.x + threadIdx.x;
    int w = gt >> 6, lane = gt & 63;
    if (w >= nT) return;
    int deg = cur[w];
    int ne = min(deg, CAPDEG);
    const int* bk = bucket + (size_t)w * CAPDEG;
    float a0 = 0.f, a1 = 0.f, a2 = 0.f, a3 = 0.f;
    int e = 0;
    for (; e + 1 < ne; e += 2) {
        int s0 = __builtin_amdgcn_readfirstlane(bk[e]);
        int s1 = __builtin_amdgcn_readfirstlane(bk[e + 1]);
        int i0 = __builtin_amdgcn_readfirstlane(posSrc[s0]);
        int i1 = __builtin_amdgcn_readfirstlane(posSrc[s1]);
        uint2 v0 = Msg[(size_t)i0 * 64 + lane];
        uint2 v1 = Msg[(size_t)i1 * 64 + lane];
        a0 += bflo(v0.x) + bflo(v1.x);
        a1 += bfhi(v0.x) + bfhi(v1.x);
        a2 += bflo(v0.y) + bflo(v1.y);
        a3 += bfhi(v0.y) + bfhi(v1.y);
    }
    for (; e < ne; e++) {
        int s = __builtin_amdgcn_readfirstlane(bk[e]);
        int i0 = __builtin_amdgcn_readfirstlane(posSrc[s]);
        uint2 v = Msg[(size_t)i0 * 64 + lane];
        a0 += bflo(v.x); a1 += bfhi(v.x); a2 += bflo(v.y); a3 += bfhi(v.y);
    }
    float nd = rsqrtf((float)max(deg, 1));
    float4 o;
    o.x = a0 * nd; o.y = a1 * nd; o.z = a2 * nd; o.w = a3 * nd;
    Agg[(size_t)w * 64 + lane] = o;
}

// ---- final: claim aggregation (bucket B0) + layer-3 GEMV + classifier head ----
__global__ void k_final(const int* __restrict__ B0, const int* __restrict__ cur0,
                        const int* __restrict__ pos1, const unsigned short* __restrict__ Msg2,
                        const float* __restrict__ W3, const float* __restrict__ b3,
                        const float* __restrict__ Wc1, const float* __restrict__ bc1,
                        const float* __restrict__ Wc2, const float* __restrict__ bc2,
                        float* __restrict__ out) {
    __shared__ float agg[H_DIM];
    __shared__ float h3[H_DIM];
    __shared__ float hid[H_HALF];
    int t = threadIdx.x;
    int deg = cur0[0];
    int ne = min(deg, CAP0);
    float a = 0.f;
    for (int e = 0; e < ne; e++) {
        int s = B0[e];
        int idx = pos1[s];
        a += bf2f(Msg2[(size_t)idx * H_DIM + t]);
    }
    agg[t] = a * rsqrtf((float)max(deg, 1));
    __syncthreads();
    float acc = b3[t];
    for (int k = 0; k < H_DIM; k++) acc += agg[k] * W3[k * H_DIM + t];
    h3[t] = fmaxf(acc, 0.f);
    __syncthreads();
    if (t < H_HALF) {
        float x = bc1[t];
        for (int k = 0; k < H_DIM; k++) x += h3[k] * Wc1[k * H_HALF + t];
        hid[t] = fmaxf(x, 0.f);
    }
    __syncthreads();
    if (t < N_CLASSES) {
        float x = bc2[t];
        for (int j = 0; j < H_HALF; j++) x += hid[j] * Wc2[j * N_CLASSES + t];
        out[t] = x;
    }
}

extern "C" void kernel_launch(void* const* d_in, const int* in_sizes, int n_in,
                              void* d_out, int out_size, void* d_ws, size_t ws_size,
                              hipStream_t stream) {
    const float* nf    = (const float*)d_in[0];
    const int*   esrc  = (const int*)d_in[1];
    const int*   edst  = (const int*)d_in[2];
    const int*   claim = (const int*)d_in[3];
    const float* W_in  = (const float*)d_in[4];
    const float* b_in  = (const float*)d_in[5];
    const float* W_gnn = (const float*)d_in[6];
    const float* b_gnn = (const float*)d_in[7];
    const float* Wc1   = (const float*)d_in[8];
    const float* bc1   = (const float*)d_in[9];
    const float* Wc2   = (const float*)d_in[10];
    const float* bc2   = (const float*)d_in[11];

    const int N = in_sizes[0] / D_IN;
    const int E = in_sizes[1];
    const int BMWP = (((N + 31) / 32) + 63) & ~63;   // bitmap words, 256B-aligned stride
    const int NBYTES = (E + 3) / 4;                  // match-byte array length

    char* p = (char*)d_ws;
    auto alloc = [&](size_t bytes) -> void* {
        void* r = (void*)p;
        p += (bytes + 255) & ~(size_t)255;
        return r;
    };
    // ---- zero region (single memset) ----
    char* zero0 = p;
    int* deg_out  = (int*)alloc((size_t)N * 4);
    unsigned* bms = (unsigned*)alloc((size_t)3 * BMWP * 4);  // bm1 | bm2 | bmL
    int* cnt      = (int*)alloc(8 * 4);      // [c1, c2, c3, cur0]
    int* cur1     = (int*)alloc((size_t)CAP1 * 4);
    int* cur2     = (int*)alloc((size_t)CAP2 * 4);
    size_t zeroBytes = (size_t)(p - zero0);
    // ---- 0xFF region (single memset) ----
    char* ff0 = p;
    int* pos1     = (int*)alloc((size_t)N * 4);
    int* pos2     = (int*)alloc((size_t)N * 4);
    int* pos3     = (int*)alloc((size_t)N * 4);
    size_t ffBytes = (size_t)(p - ff0);
    // ---- uninitialized ----
    unsigned* bm1 = bms;
    unsigned* bm2 = bms + BMWP;
    unsigned* bmL = bms + 2 * BMWP;
    int* list1    = (int*)alloc((size_t)CAP1 * 4);
    int* list2    = (int*)alloc((size_t)CAP2 * 4);
    int* list3    = (int*)alloc((size_t)N * 4);
    int* B0       = (int*)alloc((size_t)CAP0 * 4);
    int* B1       = (int*)alloc((size_t)CAP1 * CAPDEG * 4);
    int* B2       = (int*)alloc((size_t)CAP2 * CAPDEG * 4);
    unsigned char* mb = (unsigned char*)alloc((size_t)NBYTES + 8);
    unsigned short* Wth_in = (unsigned short*)alloc((size_t)D_IN * H_DIM * 2);
    unsigned short* Wtl_in = (unsigned short*)alloc((size_t)D_IN * H_DIM * 2);
    unsigned short* Wth_g  = (unsigned short*)alloc((size_t)2 * H_DIM * H_DIM * 2);
    unsigned short* Wtl_g  = (unsigned short*)alloc((size_t)2 * H_DIM * H_DIM * 2);
    unsigned short* Msg0 = (unsigned short*)alloc((size_t)N * H_DIM * 2);
    unsigned short* Msg1 = (unsigned short*)alloc((size_t)CAP2 * H_DIM * 2);
    unsigned short* Msg2 = (unsigned short*)alloc((size_t)CAP1 * H_DIM * 2);
    float* Agg1 = (float*)alloc((size_t)CAP2 * H_DIM * 4);
    float* Agg2 = (float*)alloc((size_t)CAP1 * H_DIM * 4);

    hipMemsetAsync(zero0, 0, zeroBytes, stream);
    hipMemsetAsync(ff0, 0xFF, ffBytes, stream);

    int e4b = ((E + 3) / 4 + 255) / 256;               // 4-edges-per-thread scans
    int exb = (((NBYTES + 3) / 4) + 255) / 256;        // word-level xexpand

    // level 1: direct in-neighbors of claim (+ fused weight split)
    k_pass1<<<e4b, 256, 0, stream>>>(esrc, edst, claim, B0, cnt + 3, pos1, list1, cnt,
                                     bm1, bmL, W_in, W_gnn, Wth_in, Wtl_in, Wth_g, Wtl_g, E);
    // level 2: branchless scan -> fused extract+expand
    k_scan_bm<<<e4b, 256, 0, stream>>>(edst, bm1, mb, E);
    k_xexpand<<<exb, 256, 0, stream>>>(mb, NBYTES, esrc, edst, pos1, B1, cur1,
                                       pos2, list2, cnt + 1, bm2, bmL);
    // level 3: branchless scan -> fused extract+expand
    k_scan_bm<<<e4b, 256, 0, stream>>>(edst, bm2, mb, E);
    k_xexpand<<<exb, 256, 0, stream>>>(mb, NBYTES, esrc, edst, pos2, B2, cur2,
                                       pos3, list3, cnt + 2, bmL, bmL);
    // out-degrees of live nodes
    k_deg<<<e4b, 256, 0, stream>>>(esrc, bmL, deg_out, E);

    // projection on S3 (single-pass bf16): Msg0[i] = (nf[list3[i]]@W_in + b_in)*rsqrt(deg)
    dim3 gproj((N + 127) / 128, 2);
    k_mfma_gemm<true, false, false, false><<<gproj, 256, 0, stream>>>(
        nf, list3, cnt + 2, Wth_in, Wtl_in, b_in, deg_out, Msg0, D_IN);

    // layer 1: aggregate S2 targets from Msg0, then GEMM (full split)
    k_gather_agg<<<(CAP2 * 64 + 255) / 256, 256, 0, stream>>>(cnt + 1, B2, cur2, pos3,
                                                              (const uint2*)Msg0, (float4*)Agg1);
    dim3 g1(CAP2 / 128, 2);
    k_mfma_gemm<false, true, true, true><<<g1, 256, 0, stream>>>(
        Agg1, list2, cnt + 1, Wth_g, Wtl_g, b_gnn, deg_out, Msg1, H_DIM);

    // layer 2: aggregate S1 targets from Msg1, then GEMM (full split)
    k_gather_agg<<<(CAP1 * 64 + 255) / 256, 256, 0, stream>>>(cnt, B1, cur1, pos2,
                                                              (const uint2*)Msg1, (float4*)Agg2);
    dim3 g2(CAP1 / 128, 2);
    k_mfma_gemm<false, true, true, true><<<g2, 256, 0, stream>>>(
        Agg2, list1, cnt, Wth_g + (size_t)H_DIM * H_DIM, Wtl_g + (size_t)H_DIM * H_DIM,
        b_gnn + H_DIM, deg_out, Msg2, H_DIM);

    // layer 3 (claim only) + classifier head
    k_final<<<1, H_DIM, 0, stream>>>(B0, cnt + 3, pos1, Msg2,
                                     W_gnn + (size_t)2 * H_DIM * H_DIM, b_gnn + 2 * H_DIM,
                                     Wc1, bc1, Wc2, bc2, (float*)d_out);
}

// Round 12
// 310.622 us; speedup vs baseline: 3.1092x; 1.0902x over previous
//
#include <hip/hip_runtime.h>
#include <hip/hip_bf16.h>

#define D_IN 768
#define H_DIM 256
#define H_HALF 128
#define N_CLASSES 3

#define CAP1 256      // max |S1| (in-neighbors of claim; realistic max ~65)
#define CAP2 16384    // max |S2| (realistic ~1-4K)
#define CAPDEG 128    // max in-degree per target (realistic max ~65)
#define CAP0 1024     // claim bucket capacity

typedef __attribute__((ext_vector_type(8))) short bf16x8;
typedef __attribute__((ext_vector_type(4))) float f32x4;

static __device__ __forceinline__ unsigned short f2bf(float f) {
    union { float f; unsigned u; } x; x.f = f;
    unsigned u = x.u;
    return (unsigned short)((u + 0x7FFFu + ((u >> 16) & 1u)) >> 16);  // RNE
}
static __device__ __forceinline__ float bf2f(unsigned short b) {
    union { unsigned u; float f; } x; x.u = ((unsigned)b) << 16;
    return x.f;
}
static __device__ __forceinline__ float bflo(unsigned v) {
    union { unsigned u; float f; } x; x.u = v << 16;
    return x.f;
}
static __device__ __forceinline__ float bfhi(unsigned v) {
    union { unsigned u; float f; } x; x.u = v & 0xFFFF0000u;
    return x.f;
}
static __device__ __forceinline__ bool bit_test(const unsigned* __restrict__ bm, int i) {
    return (bm[i >> 5] >> (i & 31)) & 1u;
}

// dedup-append node s to frontier list; set bits in bmCur and bmL
static __device__ __forceinline__ void try_append(int s, int* __restrict__ pos,
                                                  int* __restrict__ list, int* __restrict__ cnt,
                                                  unsigned* __restrict__ bmCur,
                                                  unsigned* __restrict__ bmL) {
    if (atomicCAS(&pos[s], -1, -2) == -1) {
        int i = atomicAdd(cnt, 1);
        list[i] = s;
        atomicOr(&bmCur[s >> 5], 1u << (s & 31));
        atomicOr(&bmL[s >> 5], 1u << (s & 31));
        atomicExch(&pos[s], i);
    }
}

// ---- pass 1 (+ fused weight split): edges into claim -> B0; srcs -> S1 ----
// 8 edges/thread; predicate is a scalar compare (proven-fast shape).
__global__ void k_pass1(const int* __restrict__ src, const int* __restrict__ dst,
                        const int* __restrict__ claim, int* __restrict__ B0,
                        int* __restrict__ cur0, int* __restrict__ pos1,
                        int* __restrict__ list1, int* __restrict__ cnt1,
                        unsigned* __restrict__ bm1, unsigned* __restrict__ bmL,
                        const float* __restrict__ W_in, const float* __restrict__ W_gnn,
                        unsigned short* __restrict__ Wth_in, unsigned short* __restrict__ Wtl_in,
                        unsigned short* __restrict__ Wth_g, unsigned short* __restrict__ Wtl_g,
                        int E) {
    int idx = blockIdx.x * 256 + threadIdx.x;
    int nth = gridDim.x * 256;
    // fused weight convert+transpose+split (independent of edge work)
    {
        const int n1 = D_IN * H_DIM;
        const int ntot = n1 + 2 * H_DIM * H_DIM;
        for (int id = idx; id < ntot; id += nth) {
            if (id < n1) {
                int k = id >> 8, n = id & 255;
                float w = W_in[id];
                unsigned short h = f2bf(w);
                Wth_in[(size_t)n * D_IN + k] = h;
                Wtl_in[(size_t)n * D_IN + k] = f2bf(w - bf2f(h));
            } else {
                int t = id - n1;
                int l = t >> 16, r = t & 65535;
                int k = r >> 8, n = r & 255;
                float w = W_gnn[(size_t)l * 65536 + r];
                unsigned short h = f2bf(w);
                Wth_g[(size_t)l * 65536 + (size_t)n * H_DIM + k] = h;
                Wtl_g[(size_t)l * 65536 + (size_t)n * H_DIM + k] = f2bf(w - bf2f(h));
            }
        }
    }
    int c = claim[0];
    int e0 = idx * 8;
    if (e0 >= E) return;
    if (e0 + 8 <= E) {
        int4 da = *(const int4*)(dst + e0);
        int4 db = *(const int4*)(dst + e0 + 4);
        int ds[8] = {da.x, da.y, da.z, da.w, db.x, db.y, db.z, db.w};
#pragma unroll
        for (int k = 0; k < 8; k++) {
            if (ds[k] == c) {
                int s = src[e0 + k];
                int p = atomicAdd(cur0, 1);
                if (p < CAP0) B0[p] = s;
                try_append(s, pos1, list1, cnt1, bm1, bmL);
            }
        }
    } else {
        for (int e = e0; e < E; e++) {
            if (dst[e] == c) {
                int s = src[e];
                int p = atomicAdd(cur0, 1);
                if (p < CAP0) B0[p] = s;
                try_append(s, pos1, list1, cnt1, bm1, bmL);
            }
        }
    }
}

// ---- fused scan+expand: phase A (branchless) computes 8-edge match byte ->
// LDS; phase B (wave 0 only, post-barrier) expands the block's sparse matches.
// Preserves the fast structure: hot loop has no load-guarded branch body.
__global__ void k_scan_expand(const int* __restrict__ src, const int* __restrict__ dst,
                              const unsigned* __restrict__ bmPrev, const int* __restrict__ posPrev,
                              int* __restrict__ bucket, int* __restrict__ cur,
                              int* __restrict__ posCur, int* __restrict__ listCur,
                              int* __restrict__ cntCur,
                              unsigned* __restrict__ bmCur, unsigned* __restrict__ bmL, int E) {
    __shared__ unsigned mwords[64];          // 256 match bytes
    int tid = threadIdx.x;
    int e0 = blockIdx.x * 2048 + tid * 8;
    unsigned m = 0;
    if (e0 + 8 <= E) {
        int4 da = *(const int4*)(dst + e0);
        int4 db = *(const int4*)(dst + e0 + 4);
        m  = bit_test(bmPrev, da.x) ? 1u : 0u;
        m |= bit_test(bmPrev, da.y) ? 2u : 0u;
        m |= bit_test(bmPrev, da.z) ? 4u : 0u;
        m |= bit_test(bmPrev, da.w) ? 8u : 0u;
        m |= bit_test(bmPrev, db.x) ? 16u : 0u;
        m |= bit_test(bmPrev, db.y) ? 32u : 0u;
        m |= bit_test(bmPrev, db.z) ? 64u : 0u;
        m |= bit_test(bmPrev, db.w) ? 128u : 0u;
    } else {
        for (int e = e0; e < E; e++)
            if (bit_test(bmPrev, dst[e])) m |= 1u << (e - e0);
    }
    ((unsigned char*)mwords)[tid] = (unsigned char)m;
    __syncthreads();
    if (tid >= 64) return;                    // waves 1-3 done
    unsigned w = mwords[tid];                 // word = threads 4t..4t+3
    int base = blockIdx.x * 2048 + tid * 32;  // 4 threads x 8 edges
    while (w) {
        int b = __ffs(w) - 1;
        w &= w - 1;
        int e = base + (b >> 3) * 8 + (b & 7);
        int s = src[e], d = dst[e];
        int pt = posPrev[d];
        int p = atomicAdd(&cur[pt], 1);
        if (p < CAPDEG) bucket[(size_t)pt * CAPDEG + p] = s;
        try_append(s, posCur, listCur, cntCur, bmCur, bmL);
    }
}

// ---- out-degrees for live nodes (predicated void atomics; proven-fast shape) ----
__global__ void k_deg(const int* __restrict__ src, const unsigned* __restrict__ bmL,
                      int* __restrict__ deg_out, int E) {
    int idx = blockIdx.x * 256 + threadIdx.x;
    int e0 = idx * 8;
    if (e0 >= E) return;
    if (e0 + 8 <= E) {
        int4 a = *(const int4*)(src + e0);
        int4 b = *(const int4*)(src + e0 + 4);
        int ss[8] = {a.x, a.y, a.z, a.w, b.x, b.y, b.z, b.w};
#pragma unroll
        for (int k = 0; k < 8; k++)
            if (bit_test(bmL, ss[k])) atomicAdd(&deg_out[ss[k]], 1);
    } else {
        for (int e = e0; e < E; e++) {
            int s = src[e];
            if (bit_test(bmL, s)) atomicAdd(&deg_out[s], 1);
        }
    }
}

// ---- split-precision MFMA GEMM over compact frontier rows ----
// Passes: Ah*Bh always; + Al*Bh if ALO; + Ah*Bl if BLO.
// Msg[row][256] = (relu?)(acc+bias) * rsqrt(deg_out[rowmap[row]])  (bf16)
template<bool GATHER_A, bool RELU, bool ALO, bool BLO>
__global__ __launch_bounds__(256) void k_mfma_gemm(
    const float* __restrict__ A, const int* __restrict__ rowmap,
    const int* __restrict__ Mptr,
    const unsigned short* __restrict__ Bth, const unsigned short* __restrict__ Btl,
    const float* __restrict__ bias, const int* __restrict__ deg_out,
    unsigned short* __restrict__ MsgOut, int K) {
    int M = Mptr[0];
    int row0 = blockIdx.x * 128;
    if (row0 >= M) return;
    int col0 = blockIdx.y * 128;

    __shared__ unsigned short Ash[128][40];
    __shared__ unsigned short Asl[ALO ? 128 : 1][40];
    __shared__ unsigned short Bsh[128][40];
    __shared__ unsigned short Bsl[BLO ? 128 : 1][40];

    int tid = threadIdx.x;
    int lane = tid & 63;
    int wv = tid >> 6;
    int wr = wv >> 1, wc = wv & 1;

    f32x4 acc[4][4];
#pragma unroll
    for (int mi = 0; mi < 4; mi++)
#pragma unroll
        for (int ni = 0; ni < 4; ni++) acc[mi][ni] = (f32x4){0.f, 0.f, 0.f, 0.f};

    int kf = (lane >> 4) * 8;
    int rsel = lane & 15;

    for (int kk = 0; kk < K; kk += 32) {
#pragma unroll
        for (int u = 0; u < 4; u++) {
            int i = tid + u * 256;
            int r = i >> 3;
            int c4 = (i & 7) * 4;
            float4 v = {0.f, 0.f, 0.f, 0.f};
            int row = row0 + r;
            if (row < M) {
                int arow = GATHER_A ? rowmap[row] : row;
                v = *(const float4*)(A + (size_t)arow * K + kk + c4);
            }
            ushort4 h;
            h.x = f2bf(v.x); h.y = f2bf(v.y); h.z = f2bf(v.z); h.w = f2bf(v.w);
            *(ushort4*)&Ash[r][c4] = h;
            if (ALO) {
                ushort4 l;
                l.x = f2bf(v.x - bf2f(h.x));
                l.y = f2bf(v.y - bf2f(h.y));
                l.z = f2bf(v.z - bf2f(h.z));
                l.w = f2bf(v.w - bf2f(h.w));
                *(ushort4*)&Asl[r][c4] = l;
            }
        }
#pragma unroll
        for (int u = 0; u < 2; u++) {
            int i = tid + u * 256;
            int r = i >> 2;
            int c8 = (i & 3) * 8;
            *(uint4*)&Bsh[r][c8] = *(const uint4*)(Bth + (size_t)(col0 + r) * K + kk + c8);
            if (BLO)
                *(uint4*)&Bsl[r][c8] = *(const uint4*)(Btl + (size_t)(col0 + r) * K + kk + c8);
        }
        __syncthreads();

        bf16x8 ah[4], al[4], bh[4], bl[4];
#pragma unroll
        for (int mi = 0; mi < 4; mi++) {
            ah[mi] = *(const bf16x8*)&Ash[wr * 64 + mi * 16 + rsel][kf];
            if (ALO) al[mi] = *(const bf16x8*)&Asl[wr * 64 + mi * 16 + rsel][kf];
        }
#pragma unroll
        for (int ni = 0; ni < 4; ni++) {
            bh[ni] = *(const bf16x8*)&Bsh[wc * 64 + ni * 16 + rsel][kf];
            if (BLO) bl[ni] = *(const bf16x8*)&Bsl[wc * 64 + ni * 16 + rsel][kf];
        }
#pragma unroll
        for (int mi = 0; mi < 4; mi++)
#pragma unroll
            for (int ni = 0; ni < 4; ni++) {
                acc[mi][ni] = __builtin_amdgcn_mfma_f32_16x16x32_bf16(ah[mi], bh[ni], acc[mi][ni], 0, 0, 0);
                if (ALO)
                    acc[mi][ni] = __builtin_amdgcn_mfma_f32_16x16x32_bf16(al[mi], bh[ni], acc[mi][ni], 0, 0, 0);
                if (BLO)
                    acc[mi][ni] = __builtin_amdgcn_mfma_f32_16x16x32_bf16(ah[mi], bl[ni], acc[mi][ni], 0, 0, 0);
            }
        __syncthreads();
    }

    int lr = (lane >> 4) * 4;
    int lc = lane & 15;
    float bcol[4];
#pragma unroll
    for (int ni = 0; ni < 4; ni++) bcol[ni] = bias[col0 + wc * 64 + ni * 16 + lc];

#pragma unroll
    for (int mi = 0; mi < 4; mi++) {
#pragma unroll
        for (int r = 0; r < 4; r++) {
            int row = row0 + wr * 64 + mi * 16 + lr + r;
            if (row >= M) continue;
            float ns = rsqrtf((float)max(deg_out[rowmap[row]], 1));
#pragma unroll
            for (int ni = 0; ni < 4; ni++) {
                int col = col0 + wc * 64 + ni * 16 + lc;
                float v = acc[mi][ni][r] + bcol[ni];
                if (RELU) v = fmaxf(v, 0.f);
                MsgOut[(size_t)row * 256 + col] = f2bf(v * ns);
            }
        }
    }
}

// ---- bucket aggregation: one wave per target; norm_dst from bucket cursor ----
__global__ void k_gather_agg(const int* __restrict__ nTptr, const int* __restrict__ bucket,
                             const int* __restrict__ cur, const int* __restrict__ posSrc,
                             const uint2* __restrict__ Msg, float4* __restrict__ Agg) {
    int nT = nTptr[0];
    int gt = blockIdx.x * blockDim.x + threadIdx.x;
    int w = gt >> 6, lane = gt & 63;
    if (w >= nT) return;
    int deg = cur[w];
    int ne = min(deg, CAPDEG);
    const int* bk = bucket + (size_t)w * CAPDEG;
    float a0 = 0.f, a1 = 0.f, a2 = 0.f, a3 = 0.f;
    int e = 0;
    for (; e + 1 < ne; e += 2) {
        int s0 = __builtin_amdgcn_readfirstlane(bk[e]);
        int s1 = __builtin_amdgcn_readfirstlane(bk[e + 1]);
        int i0 = __builtin_amdgcn_readfirstlane(posSrc[s0]);
        int i1 = __builtin_amdgcn_readfirstlane(posSrc[s1]);
        uint2 v0 = Msg[(size_t)i0 * 64 + lane];
        uint2 v1 = Msg[(size_t)i1 * 64 + lane];
        a0 += bflo(v0.x) + bflo(v1.x);
        a1 += bfhi(v0.x) + bfhi(v1.x);
        a2 += bflo(v0.y) + bflo(v1.y);
        a3 += bfhi(v0.y) + bfhi(v1.y);
    }
    for (; e < ne; e++) {
        int s = __builtin_amdgcn_readfirstlane(bk[e]);
        int i0 = __builtin_amdgcn_readfirstlane(posSrc[s]);
        uint2 v = Msg[(size_t)i0 * 64 + lane];
        a0 += bflo(v.x); a1 += bfhi(v.x); a2 += bflo(v.y); a3 += bfhi(v.y);
    }
    float nd = rsqrtf((float)max(deg, 1));
    float4 o;
    o.x = a0 * nd; o.y = a1 * nd; o.z = a2 * nd; o.w = a3 * nd;
    Agg[(size_t)w * 64 + lane] = o;
}

// ---- final: claim aggregation (bucket B0) + layer-3 GEMV + classifier head ----
__global__ void k_final(const int* __restrict__ B0, const int* __restrict__ cur0,
                        const int* __restrict__ pos1, const unsigned short* __restrict__ Msg2,
                        const float* __restrict__ W3, const float* __restrict__ b3,
                        const float* __restrict__ Wc1, const float* __restrict__ bc1,
                        const float* __restrict__ Wc2, const float* __restrict__ bc2,
                        float* __restrict__ out) {
    __shared__ float agg[H_DIM];
    __shared__ float h3[H_DIM];
    __shared__ float hid[H_HALF];
    int t = threadIdx.x;
    int deg = cur0[0];
    int ne = min(deg, CAP0);
    float a = 0.f;
    for (int e = 0; e < ne; e++) {
        int s = B0[e];
        int idx = pos1[s];
        a += bf2f(Msg2[(size_t)idx * H_DIM + t]);
    }
    agg[t] = a * rsqrtf((float)max(deg, 1));
    __syncthreads();
    float acc = b3[t];
    for (int k = 0; k < H_DIM; k++) acc += agg[k] * W3[k * H_DIM + t];
    h3[t] = fmaxf(acc, 0.f);
    __syncthreads();
    if (t < H_HALF) {
        float x = bc1[t];
        for (int k = 0; k < H_DIM; k++) x += h3[k] * Wc1[k * H_HALF + t];
        hid[t] = fmaxf(x, 0.f);
    }
    __syncthreads();
    if (t < N_CLASSES) {
        float x = bc2[t];
        for (int j = 0; j < H_HALF; j++) x += hid[j] * Wc2[j * N_CLASSES + t];
        out[t] = x;
    }
}

extern "C" void kernel_launch(void* const* d_in, const int* in_sizes, int n_in,
                              void* d_out, int out_size, void* d_ws, size_t ws_size,
                              hipStream_t stream) {
    const float* nf    = (const float*)d_in[0];
    const int*   esrc  = (const int*)d_in[1];
    const int*   edst  = (const int*)d_in[2];
    const int*   claim = (const int*)d_in[3];
    const float* W_in  = (const float*)d_in[4];
    const float* b_in  = (const float*)d_in[5];
    const float* W_gnn = (const float*)d_in[6];
    const float* b_gnn = (const float*)d_in[7];
    const float* Wc1   = (const float*)d_in[8];
    const float* bc1   = (const float*)d_in[9];
    const float* Wc2   = (const float*)d_in[10];
    const float* bc2   = (const float*)d_in[11];

    const int N = in_sizes[0] / D_IN;
    const int E = in_sizes[1];
    const int BMWP = (((N + 31) / 32) + 63) & ~63;   // bitmap words, 256B-aligned stride

    char* p = (char*)d_ws;
    auto alloc = [&](size_t bytes) -> void* {
        void* r = (void*)p;
        p += (bytes + 255) & ~(size_t)255;
        return r;
    };
    // ---- zero region (single memset) ----
    char* zero0 = p;
    int* deg_out  = (int*)alloc((size_t)N * 4);
    unsigned* bms = (unsigned*)alloc((size_t)3 * BMWP * 4);  // bm1 | bm2 | bmL
    int* cnt      = (int*)alloc(8 * 4);      // [c1, c2, c3, cur0]
    int* cur1     = (int*)alloc((size_t)CAP1 * 4);
    int* cur2     = (int*)alloc((size_t)CAP2 * 4);
    size_t zeroBytes = (size_t)(p - zero0);
    // ---- 0xFF region (single memset) ----
    char* ff0 = p;
    int* pos1     = (int*)alloc((size_t)N * 4);
    int* pos2     = (int*)alloc((size_t)N * 4);
    int* pos3     = (int*)alloc((size_t)N * 4);
    size_t ffBytes = (size_t)(p - ff0);
    // ---- uninitialized ----
    unsigned* bm1 = bms;
    unsigned* bm2 = bms + BMWP;
    unsigned* bmL = bms + 2 * BMWP;
    int* list1    = (int*)alloc((size_t)CAP1 * 4);
    int* list2    = (int*)alloc((size_t)CAP2 * 4);
    int* list3    = (int*)alloc((size_t)N * 4);
    int* B0       = (int*)alloc((size_t)CAP0 * 4);
    int* B1       = (int*)alloc((size_t)CAP1 * CAPDEG * 4);
    int* B2       = (int*)alloc((size_t)CAP2 * CAPDEG * 4);
    unsigned short* Wth_in = (unsigned short*)alloc((size_t)D_IN * H_DIM * 2);
    unsigned short* Wtl_in = (unsigned short*)alloc((size_t)D_IN * H_DIM * 2);
    unsigned short* Wth_g  = (unsigned short*)alloc((size_t)2 * H_DIM * H_DIM * 2);
    unsigned short* Wtl_g  = (unsigned short*)alloc((size_t)2 * H_DIM * H_DIM * 2);
    unsigned short* Msg0 = (unsigned short*)alloc((size_t)N * H_DIM * 2);
    unsigned short* Msg1 = (unsigned short*)alloc((size_t)CAP2 * H_DIM * 2);
    unsigned short* Msg2 = (unsigned short*)alloc((size_t)CAP1 * H_DIM * 2);
    float* Agg1 = (float*)alloc((size_t)CAP2 * H_DIM * 4);
    float* Agg2 = (float*)alloc((size_t)CAP1 * H_DIM * 4);

    hipMemsetAsync(zero0, 0, zeroBytes, stream);
    hipMemsetAsync(ff0, 0xFF, ffBytes, stream);

    int e8b = (E + 2047) / 2048;   // 8 edges/thread, 256 threads/block

    // level 1: direct in-neighbors of claim (+ fused weight split)
    k_pass1<<<e8b, 256, 0, stream>>>(esrc, edst, claim, B0, cnt + 3, pos1, list1, cnt,
                                     bm1, bmL, W_in, W_gnn, Wth_in, Wtl_in, Wth_g, Wtl_g, E);
    // level 2: fused branchless scan + sparse expand
    k_scan_expand<<<e8b, 256, 0, stream>>>(esrc, edst, bm1, pos1, B1, cur1,
                                           pos2, list2, cnt + 1, bm2, bmL, E);
    // level 3: fused branchless scan + sparse expand
    k_scan_expand<<<e8b, 256, 0, stream>>>(esrc, edst, bm2, pos2, B2, cur2,
                                           pos3, list3, cnt + 2, bmL, bmL, E);
    // out-degrees of live nodes
    k_deg<<<e8b, 256, 0, stream>>>(esrc, bmL, deg_out, E);

    // projection on S3 (single-pass bf16): Msg0[i] = (nf[list3[i]]@W_in + b_in)*rsqrt(deg)
    dim3 gproj((N + 127) / 128, 2);
    k_mfma_gemm<true, false, false, false><<<gproj, 256, 0, stream>>>(
        nf, list3, cnt + 2, Wth_in, Wtl_in, b_in, deg_out, Msg0, D_IN);

    // layer 1: aggregate S2 targets from Msg0, then GEMM (full split)
    k_gather_agg<<<(CAP2 * 64 + 255) / 256, 256, 0, stream>>>(cnt + 1, B2, cur2, pos3,
                                                              (const uint2*)Msg0, (float4*)Agg1);
    dim3 g1(CAP2 / 128, 2);
    k_mfma_gemm<false, true, true, true><<<g1, 256, 0, stream>>>(
        Agg1, list2, cnt + 1, Wth_g, Wtl_g, b_gnn, deg_out, Msg1, H_DIM);

    // layer 2: aggregate S1 targets from Msg1, then GEMM (full split)
    k_gather_agg<<<(CAP1 * 64 + 255) / 256, 256, 0, stream>>>(cnt, B1, cur1, pos2,
                                                              (const uint2*)Msg1, (float4*)Agg2);
    dim3 g2(CAP1 / 128, 2);
    k_mfma_gemm<false, true, true, true><<<g2, 256, 0, stream>>>(
        Agg2, list1, cnt, Wth_g + (size_t)H_DIM * H_DIM, Wtl_g + (size_t)H_DIM * H_DIM,
        b_gnn + H_DIM, deg_out, Msg2, H_DIM);

    // layer 3 (claim only) + classifier head
    k_final<<<1, H_DIM, 0, stream>>>(B0, cnt + 3, pos1, Msg2,
                                     W_gnn + (size_t)2 * H_DIM * H_DIM, b_gnn + 2 * H_DIM,
                                     Wc1, bc1, Wc2, bc2, (float*)d_out);
}

// Round 13
// 272.538 us; speedup vs baseline: 3.5436x; 1.1397x over previous
//
#include <hip/hip_runtime.h>
#include <hip/hip_bf16.h>

#define D_IN 768
#define H_DIM 256
#define H_HALF 128
#define N_CLASSES 3

#define CAP1 256      // max |S1| (in-neighbors of claim; realistic max ~65)
#define CAP2 16384    // max |S2| (realistic ~1-4K)
#define CAPDEG 128    // max in-degree per target (realistic max ~65)
#define CAP0 1024     // claim bucket capacity

typedef __attribute__((ext_vector_type(8))) short bf16x8;
typedef __attribute__((ext_vector_type(4))) float f32x4;

static __device__ __forceinline__ unsigned short f2bf(float f) {
    union { float f; unsigned u; } x; x.f = f;
    unsigned u = x.u;
    return (unsigned short)((u + 0x7FFFu + ((u >> 16) & 1u)) >> 16);  // RNE
}
static __device__ __forceinline__ float bf2f(unsigned short b) {
    union { unsigned u; float f; } x; x.u = ((unsigned)b) << 16;
    return x.f;
}
static __device__ __forceinline__ float bflo(unsigned v) {
    union { unsigned u; float f; } x; x.u = v << 16;
    return x.f;
}
static __device__ __forceinline__ float bfhi(unsigned v) {
    union { unsigned u; float f; } x; x.u = v & 0xFFFF0000u;
    return x.f;
}
static __device__ __forceinline__ bool bit_test(const unsigned* __restrict__ bm, int i) {
    return (bm[i >> 5] >> (i & 31)) & 1u;
}

// dedup-append node s to frontier list; set bits in bmCur and bmL
static __device__ __forceinline__ void try_append(int s, int* __restrict__ pos,
                                                  int* __restrict__ list, int* __restrict__ cnt,
                                                  unsigned* __restrict__ bmCur,
                                                  unsigned* __restrict__ bmL) {
    if (atomicCAS(&pos[s], -1, -2) == -1) {
        int i = atomicAdd(cnt, 1);
        list[i] = s;
        atomicOr(&bmCur[s >> 5], 1u << (s & 31));
        atomicOr(&bmL[s >> 5], 1u << (s & 31));
        atomicExch(&pos[s], i);
    }
}

// ---- pass 1 (+ fused weight split): edges into claim -> B0; srcs -> S1 ----
__global__ void k_pass1(const int* __restrict__ src, const int* __restrict__ dst,
                        const int* __restrict__ claim, int* __restrict__ B0,
                        int* __restrict__ cur0, int* __restrict__ pos1,
                        int* __restrict__ list1, int* __restrict__ cnt1,
                        unsigned* __restrict__ bm1, unsigned* __restrict__ bmL,
                        const float* __restrict__ W_in, const float* __restrict__ W_gnn,
                        unsigned short* __restrict__ Wth_in, unsigned short* __restrict__ Wtl_in,
                        unsigned short* __restrict__ Wth_g, unsigned short* __restrict__ Wtl_g,
                        int E) {
    int idx = blockIdx.x * 256 + threadIdx.x;
    int nth = gridDim.x * 256;
    // fused weight convert+transpose+split (independent of edge work)
    {
        const int n1 = D_IN * H_DIM;
        const int ntot = n1 + 2 * H_DIM * H_DIM;
        for (int id = idx; id < ntot; id += nth) {
            if (id < n1) {
                int k = id >> 8, n = id & 255;
                float w = W_in[id];
                unsigned short h = f2bf(w);
                Wth_in[(size_t)n * D_IN + k] = h;
                Wtl_in[(size_t)n * D_IN + k] = f2bf(w - bf2f(h));
            } else {
                int t = id - n1;
                int l = t >> 16, r = t & 65535;
                int k = r >> 8, n = r & 255;
                float w = W_gnn[(size_t)l * 65536 + r];
                unsigned short h = f2bf(w);
                Wth_g[(size_t)l * 65536 + (size_t)n * H_DIM + k] = h;
                Wtl_g[(size_t)l * 65536 + (size_t)n * H_DIM + k] = f2bf(w - bf2f(h));
            }
        }
    }
    int c = claim[0];
    int e0 = idx * 8;
    if (e0 >= E) return;
    if (e0 + 8 <= E) {
        int4 da = *(const int4*)(dst + e0);
        int4 db = *(const int4*)(dst + e0 + 4);
        int ds[8] = {da.x, da.y, da.z, da.w, db.x, db.y, db.z, db.w};
#pragma unroll
        for (int k = 0; k < 8; k++) {
            if (ds[k] == c) {
                int s = src[e0 + k];
                int p = atomicAdd(cur0, 1);
                if (p < CAP0) B0[p] = s;
                try_append(s, pos1, list1, cnt1, bm1, bmL);
            }
        }
    } else {
        for (int e = e0; e < E; e++) {
            if (dst[e] == c) {
                int s = src[e];
                int p = atomicAdd(cur0, 1);
                if (p < CAP0) B0[p] = s;
                try_append(s, pos1, list1, cnt1, bm1, bmL);
            }
        }
    }
}

// ---- fused scan+expand: phase A (branchless) match byte -> LDS; phase B
// (wave 0, post-barrier) expands the block's sparse matches. ----
__global__ void k_scan_expand(const int* __restrict__ src, const int* __restrict__ dst,
                              const unsigned* __restrict__ bmPrev, const int* __restrict__ posPrev,
                              int* __restrict__ bucket, int* __restrict__ cur,
                              int* __restrict__ posCur, int* __restrict__ listCur,
                              int* __restrict__ cntCur,
                              unsigned* __restrict__ bmCur, unsigned* __restrict__ bmL, int E) {
    __shared__ unsigned mwords[64];          // 256 match bytes
    int tid = threadIdx.x;
    int e0 = blockIdx.x * 2048 + tid * 8;
    unsigned m = 0;
    if (e0 + 8 <= E) {
        int4 da = *(const int4*)(dst + e0);
        int4 db = *(const int4*)(dst + e0 + 4);
        m  = bit_test(bmPrev, da.x) ? 1u : 0u;
        m |= bit_test(bmPrev, da.y) ? 2u : 0u;
        m |= bit_test(bmPrev, da.z) ? 4u : 0u;
        m |= bit_test(bmPrev, da.w) ? 8u : 0u;
        m |= bit_test(bmPrev, db.x) ? 16u : 0u;
        m |= bit_test(bmPrev, db.y) ? 32u : 0u;
        m |= bit_test(bmPrev, db.z) ? 64u : 0u;
        m |= bit_test(bmPrev, db.w) ? 128u : 0u;
    } else {
        for (int e = e0; e < E; e++)
            if (bit_test(bmPrev, dst[e])) m |= 1u << (e - e0);
    }
    ((unsigned char*)mwords)[tid] = (unsigned char)m;
    __syncthreads();
    if (tid >= 64) return;                    // waves 1-3 done
    unsigned w = mwords[tid];                 // word = threads 4t..4t+3
    int base = blockIdx.x * 2048 + tid * 32;  // 4 threads x 8 edges
    while (w) {
        int b = __ffs(w) - 1;
        w &= w - 1;
        int e = base + (b >> 3) * 8 + (b & 7);
        int s = src[e], d = dst[e];
        int pt = posPrev[d];
        int p = atomicAdd(&cur[pt], 1);
        if (p < CAPDEG) bucket[(size_t)pt * CAPDEG + p] = s;
        try_append(s, posCur, listCur, cntCur, bmCur, bmL);
    }
}

// ---- out-degrees for live nodes (predicated void atomics; proven-fast shape) ----
__global__ void k_deg(const int* __restrict__ src, const unsigned* __restrict__ bmL,
                      int* __restrict__ deg_out, int E) {
    int idx = blockIdx.x * 256 + threadIdx.x;
    int e0 = idx * 8;
    if (e0 >= E) return;
    if (e0 + 8 <= E) {
        int4 a = *(const int4*)(src + e0);
        int4 b = *(const int4*)(src + e0 + 4);
        int ss[8] = {a.x, a.y, a.z, a.w, b.x, b.y, b.z, b.w};
#pragma unroll
        for (int k = 0; k < 8; k++)
            if (bit_test(bmL, ss[k])) atomicAdd(&deg_out[ss[k]], 1);
    } else {
        for (int e = e0; e < E; e++) {
            int s = src[e];
            if (bit_test(bmL, s)) atomicAdd(&deg_out[s], 1);
        }
    }
}

// ---- split-precision MFMA GEMM, BM=64 tile for occupancy ----
// 4 waves; each wave owns the full 64 rows x its 32-col quarter of the
// 64x128 output tile. Passes: Ah*Bh always; + Al*Bh if ALO; + Ah*Bl if BLO.
// Msg[row][256] = (relu?)(acc+bias) * rsqrt(deg_out[rowmap[row]])  (bf16)
template<bool GATHER_A, bool RELU, bool ALO, bool BLO>
__global__ __launch_bounds__(256) void k_mfma_gemm(
    const float* __restrict__ A, const int* __restrict__ rowmap,
    const int* __restrict__ Mptr,
    const unsigned short* __restrict__ Bth, const unsigned short* __restrict__ Btl,
    const float* __restrict__ bias, const int* __restrict__ deg_out,
    unsigned short* __restrict__ MsgOut, int K) {
    int M = Mptr[0];
    int row0 = blockIdx.x * 64;
    if (row0 >= M) return;
    int col0 = blockIdx.y * 128;

    __shared__ unsigned short Ash[64][40];
    __shared__ unsigned short Asl[ALO ? 64 : 1][40];
    __shared__ unsigned short Bsh[128][40];
    __shared__ unsigned short Bsl[BLO ? 128 : 1][40];

    int tid = threadIdx.x;
    int lane = tid & 63;
    int wv = tid >> 6;          // wave's 32-col quarter

    f32x4 acc[4][2];
#pragma unroll
    for (int mi = 0; mi < 4; mi++)
#pragma unroll
        for (int ni = 0; ni < 2; ni++) acc[mi][ni] = (f32x4){0.f, 0.f, 0.f, 0.f};

    int kf = (lane >> 4) * 8;
    int rsel = lane & 15;

    for (int kk = 0; kk < K; kk += 32) {
        // stage A: 64 rows x 32 cols fp32 = 512 float4, 2 per thread
#pragma unroll
        for (int u = 0; u < 2; u++) {
            int i = tid + u * 256;
            int r = i >> 3;
            int c4 = (i & 7) * 4;
            float4 v = {0.f, 0.f, 0.f, 0.f};
            int row = row0 + r;
            if (row < M) {
                int arow = GATHER_A ? rowmap[row] : row;
                v = *(const float4*)(A + (size_t)arow * K + kk + c4);
            }
            ushort4 h;
            h.x = f2bf(v.x); h.y = f2bf(v.y); h.z = f2bf(v.z); h.w = f2bf(v.w);
            *(ushort4*)&Ash[r][c4] = h;
            if (ALO) {
                ushort4 l;
                l.x = f2bf(v.x - bf2f(h.x));
                l.y = f2bf(v.y - bf2f(h.y));
                l.z = f2bf(v.z - bf2f(h.z));
                l.w = f2bf(v.w - bf2f(h.w));
                *(ushort4*)&Asl[r][c4] = l;
            }
        }
        // stage B: 128 n-rows x 32 k, 2 uint4 per thread per buffer
#pragma unroll
        for (int u = 0; u < 2; u++) {
            int i = tid + u * 256;
            int r = i >> 2;
            int c8 = (i & 3) * 8;
            *(uint4*)&Bsh[r][c8] = *(const uint4*)(Bth + (size_t)(col0 + r) * K + kk + c8);
            if (BLO)
                *(uint4*)&Bsl[r][c8] = *(const uint4*)(Btl + (size_t)(col0 + r) * K + kk + c8);
        }
        __syncthreads();

        bf16x8 ah[4], al[4], bh[2], bl[2];
#pragma unroll
        for (int mi = 0; mi < 4; mi++) {
            ah[mi] = *(const bf16x8*)&Ash[mi * 16 + rsel][kf];
            if (ALO) al[mi] = *(const bf16x8*)&Asl[mi * 16 + rsel][kf];
        }
#pragma unroll
        for (int ni = 0; ni < 2; ni++) {
            bh[ni] = *(const bf16x8*)&Bsh[wv * 32 + ni * 16 + rsel][kf];
            if (BLO) bl[ni] = *(const bf16x8*)&Bsl[wv * 32 + ni * 16 + rsel][kf];
        }
#pragma unroll
        for (int mi = 0; mi < 4; mi++)
#pragma unroll
            for (int ni = 0; ni < 2; ni++) {
                acc[mi][ni] = __builtin_amdgcn_mfma_f32_16x16x32_bf16(ah[mi], bh[ni], acc[mi][ni], 0, 0, 0);
                if (ALO)
                    acc[mi][ni] = __builtin_amdgcn_mfma_f32_16x16x32_bf16(al[mi], bh[ni], acc[mi][ni], 0, 0, 0);
                if (BLO)
                    acc[mi][ni] = __builtin_amdgcn_mfma_f32_16x16x32_bf16(ah[mi], bl[ni], acc[mi][ni], 0, 0, 0);
            }
        __syncthreads();
    }

    int lr = (lane >> 4) * 4;
    int lc = lane & 15;
    float bcol[2];
#pragma unroll
    for (int ni = 0; ni < 2; ni++) bcol[ni] = bias[col0 + wv * 32 + ni * 16 + lc];

#pragma unroll
    for (int mi = 0; mi < 4; mi++) {
#pragma unroll
        for (int r = 0; r < 4; r++) {
            int row = row0 + mi * 16 + lr + r;
            if (row >= M) continue;
            float ns = rsqrtf((float)max(deg_out[rowmap[row]], 1));
#pragma unroll
            for (int ni = 0; ni < 2; ni++) {
                int col = col0 + wv * 32 + ni * 16 + lc;
                float v = acc[mi][ni][r] + bcol[ni];
                if (RELU) v = fmaxf(v, 0.f);
                MsgOut[(size_t)row * 256 + col] = f2bf(v * ns);
            }
        }
    }
}

// ---- bucket aggregation: one wave per target; norm_dst from bucket cursor ----
__global__ void k_gather_agg(const int* __restrict__ nTptr, const int* __restrict__ bucket,
                             const int* __restrict__ cur, const int* __restrict__ posSrc,
                             const uint2* __restrict__ Msg, float4* __restrict__ Agg) {
    int nT = nTptr[0];
    int gt = blockIdx.x * blockDim.x + threadIdx.x;
    int w = gt >> 6, lane = gt & 63;
    if (w >= nT) return;
    int deg = cur[w];
    int ne = min(deg, CAPDEG);
    const int* bk = bucket + (size_t)w * CAPDEG;
    float a0 = 0.f, a1 = 0.f, a2 = 0.f, a3 = 0.f;
    int e = 0;
    for (; e + 1 < ne; e += 2) {
        int s0 = __builtin_amdgcn_readfirstlane(bk[e]);
        int s1 = __builtin_amdgcn_readfirstlane(bk[e + 1]);
        int i0 = __builtin_amdgcn_readfirstlane(posSrc[s0]);
        int i1 = __builtin_amdgcn_readfirstlane(posSrc[s1]);
        uint2 v0 = Msg[(size_t)i0 * 64 + lane];
        uint2 v1 = Msg[(size_t)i1 * 64 + lane];
        a0 += bflo(v0.x) + bflo(v1.x);
        a1 += bfhi(v0.x) + bfhi(v1.x);
        a2 += bflo(v0.y) + bflo(v1.y);
        a3 += bfhi(v0.y) + bfhi(v1.y);
    }
    for (; e < ne; e++) {
        int s = __builtin_amdgcn_readfirstlane(bk[e]);
        int i0 = __builtin_amdgcn_readfirstlane(posSrc[s]);
        uint2 v = Msg[(size_t)i0 * 64 + lane];
        a0 += bflo(v.x); a1 += bfhi(v.x); a2 += bflo(v.y); a3 += bfhi(v.y);
    }
    float nd = rsqrtf((float)max(deg, 1));
    float4 o;
    o.x = a0 * nd; o.y = a1 * nd; o.z = a2 * nd; o.w = a3 * nd;
    Agg[(size_t)w * 64 + lane] = o;
}

// ---- final: claim aggregation (bucket B0) + layer-3 GEMV + classifier head ----
__global__ void k_final(const int* __restrict__ B0, const int* __restrict__ cur0,
                        const int* __restrict__ pos1, const unsigned short* __restrict__ Msg2,
                        const float* __restrict__ W3, const float* __restrict__ b3,
                        const float* __restrict__ Wc1, const float* __restrict__ bc1,
                        const float* __restrict__ Wc2, const float* __restrict__ bc2,
                        float* __restrict__ out) {
    __shared__ float agg[H_DIM];
    __shared__ float h3[H_DIM];
    __shared__ float hid[H_HALF];
    int t = threadIdx.x;
    int deg = cur0[0];
    int ne = min(deg, CAP0);
    float a = 0.f;
    for (int e = 0; e < ne; e++) {
        int s = B0[e];
        int idx = pos1[s];
        a += bf2f(Msg2[(size_t)idx * H_DIM + t]);
    }
    agg[t] = a * rsqrtf((float)max(deg, 1));
    __syncthreads();
    float acc = b3[t];
    for (int k = 0; k < H_DIM; k++) acc += agg[k] * W3[k * H_DIM + t];
    h3[t] = fmaxf(acc, 0.f);
    __syncthreads();
    if (t < H_HALF) {
        float x = bc1[t];
        for (int k = 0; k < H_DIM; k++) x += h3[k] * Wc1[k * H_HALF + t];
        hid[t] = fmaxf(x, 0.f);
    }
    __syncthreads();
    if (t < N_CLASSES) {
        float x = bc2[t];
        for (int j = 0; j < H_HALF; j++) x += hid[j] * Wc2[j * N_CLASSES + t];
        out[t] = x;
    }
}

extern "C" void kernel_launch(void* const* d_in, const int* in_sizes, int n_in,
                              void* d_out, int out_size, void* d_ws, size_t ws_size,
                              hipStream_t stream) {
    const float* nf    = (const float*)d_in[0];
    const int*   esrc  = (const int*)d_in[1];
    const int*   edst  = (const int*)d_in[2];
    const int*   claim = (const int*)d_in[3];
    const float* W_in  = (const float*)d_in[4];
    const float* b_in  = (const float*)d_in[5];
    const float* W_gnn = (const float*)d_in[6];
    const float* b_gnn = (const float*)d_in[7];
    const float* Wc1   = (const float*)d_in[8];
    const float* bc1   = (const float*)d_in[9];
    const float* Wc2   = (const float*)d_in[10];
    const float* bc2   = (const float*)d_in[11];

    const int N = in_sizes[0] / D_IN;
    const int E = in_sizes[1];
    const int BMWP = (((N + 31) / 32) + 63) & ~63;   // bitmap words, 256B-aligned stride

    char* p = (char*)d_ws;
    auto alloc = [&](size_t bytes) -> void* {
        void* r = (void*)p;
        p += (bytes + 255) & ~(size_t)255;
        return r;
    };
    // ---- zero region (single memset) ----
    char* zero0 = p;
    int* deg_out  = (int*)alloc((size_t)N * 4);
    unsigned* bms = (unsigned*)alloc((size_t)3 * BMWP * 4);  // bm1 | bm2 | bmL
    int* cnt      = (int*)alloc(8 * 4);      // [c1, c2, c3, cur0]
    int* cur1     = (int*)alloc((size_t)CAP1 * 4);
    int* cur2     = (int*)alloc((size_t)CAP2 * 4);
    size_t zeroBytes = (size_t)(p - zero0);
    // ---- 0xFF region (single memset) ----
    char* ff0 = p;
    int* pos1     = (int*)alloc((size_t)N * 4);
    int* pos2     = (int*)alloc((size_t)N * 4);
    int* pos3     = (int*)alloc((size_t)N * 4);
    size_t ffBytes = (size_t)(p - ff0);
    // ---- uninitialized ----
    unsigned* bm1 = bms;
    unsigned* bm2 = bms + BMWP;
    unsigned* bmL = bms + 2 * BMWP;
    int* list1    = (int*)alloc((size_t)CAP1 * 4);
    int* list2    = (int*)alloc((size_t)CAP2 * 4);
    int* list3    = (int*)alloc((size_t)N * 4);
    int* B0       = (int*)alloc((size_t)CAP0 * 4);
    int* B1       = (int*)alloc((size_t)CAP1 * CAPDEG * 4);
    int* B2       = (int*)alloc((size_t)CAP2 * CAPDEG * 4);
    unsigned short* Wth_in = (unsigned short*)alloc((size_t)D_IN * H_DIM * 2);
    unsigned short* Wtl_in = (unsigned short*)alloc((size_t)D_IN * H_DIM * 2);
    unsigned short* Wth_g  = (unsigned short*)alloc((size_t)2 * H_DIM * H_DIM * 2);
    unsigned short* Wtl_g  = (unsigned short*)alloc((size_t)2 * H_DIM * H_DIM * 2);
    unsigned short* Msg0 = (unsigned short*)alloc((size_t)N * H_DIM * 2);
    unsigned short* Msg1 = (unsigned short*)alloc((size_t)CAP2 * H_DIM * 2);
    unsigned short* Msg2 = (unsigned short*)alloc((size_t)CAP1 * H_DIM * 2);
    float* Agg1 = (float*)alloc((size_t)CAP2 * H_DIM * 4);
    float* Agg2 = (float*)alloc((size_t)CAP1 * H_DIM * 4);

    hipMemsetAsync(zero0, 0, zeroBytes, stream);
    hipMemsetAsync(ff0, 0xFF, ffBytes, stream);

    int e8b = (E + 2047) / 2048;   // 8 edges/thread, 256 threads/block

    // level 1: direct in-neighbors of claim (+ fused weight split)
    k_pass1<<<e8b, 256, 0, stream>>>(esrc, edst, claim, B0, cnt + 3, pos1, list1, cnt,
                                     bm1, bmL, W_in, W_gnn, Wth_in, Wtl_in, Wth_g, Wtl_g, E);
    // level 2: fused branchless scan + sparse expand
    k_scan_expand<<<e8b, 256, 0, stream>>>(esrc, edst, bm1, pos1, B1, cur1,
                                           pos2, list2, cnt + 1, bm2, bmL, E);
    // level 3: fused branchless scan + sparse expand
    k_scan_expand<<<e8b, 256, 0, stream>>>(esrc, edst, bm2, pos2, B2, cur2,
                                           pos3, list3, cnt + 2, bmL, bmL, E);
    // out-degrees of live nodes
    k_deg<<<e8b, 256, 0, stream>>>(esrc, bmL, deg_out, E);

    // projection on S3 (single-pass bf16, BM=64): Msg0[i] = (nf[l3[i]]@W_in + b_in)*rsqrt(deg)
    dim3 gproj((N + 63) / 64, 2);
    k_mfma_gemm<true, false, false, false><<<gproj, 256, 0, stream>>>(
        nf, list3, cnt + 2, Wth_in, Wtl_in, b_in, deg_out, Msg0, D_IN);

    // layer 1: aggregate S2 targets from Msg0, then GEMM (full split, BM=64)
    k_gather_agg<<<(CAP2 * 64 + 255) / 256, 256, 0, stream>>>(cnt + 1, B2, cur2, pos3,
                                                              (const uint2*)Msg0, (float4*)Agg1);
    dim3 g1(CAP2 / 64, 2);
    k_mfma_gemm<false, true, true, true><<<g1, 256, 0, stream>>>(
        Agg1, list2, cnt + 1, Wth_g, Wtl_g, b_gnn, deg_out, Msg1, H_DIM);

    // layer 2: aggregate S1 targets from Msg1, then GEMM (full split, BM=64)
    k_gather_agg<<<(CAP1 * 64 + 255) / 256, 256, 0, stream>>>(cnt, B1, cur1, pos2,
                                                              (const uint2*)Msg1, (float4*)Agg2);
    dim3 g2(CAP1 / 64, 2);
    k_mfma_gemm<false, true, true, true><<<g2, 256, 0, stream>>>(
        Agg2, list1, cnt, Wth_g + (size_t)H_DIM * H_DIM, Wtl_g + (size_t)H_DIM * H_DIM,
        b_gnn + H_DIM, deg_out, Msg2, H_DIM);

    // layer 3 (claim only) + classifier head
    k_final<<<1, H_DIM, 0, stream>>>(B0, cnt + 3, pos1, Msg2,
                                     W_gnn + (size_t)2 * H_DIM * H_DIM, b_gnn + 2 * H_DIM,
                                     Wc1, bc1, Wc2, bc2, (float*)d_out);
}

// Round 14
// 271.378 us; speedup vs baseline: 3.5588x; 1.0043x over previous
//
#include <hip/hip_runtime.h>
#include <hip/hip_bf16.h>

#define D_IN 768
#define H_DIM 256
#define H_HALF 128
#define N_CLASSES 3

#define CAP1 256      // max |S1| (in-neighbors of claim; realistic max ~65)
#define CAP2 16384    // max |S2| (realistic ~1-4K)
#define CAPDEG 128    // max in-degree per target (realistic max ~65)
#define CAP0 1024     // claim bucket capacity

typedef __attribute__((ext_vector_type(8))) short bf16x8;
typedef __attribute__((ext_vector_type(4))) float f32x4;

static __device__ __forceinline__ unsigned short f2bf(float f) {
    union { float f; unsigned u; } x; x.f = f;
    unsigned u = x.u;
    return (unsigned short)((u + 0x7FFFu + ((u >> 16) & 1u)) >> 16);  // RNE
}
static __device__ __forceinline__ float bf2f(unsigned short b) {
    union { unsigned u; float f; } x; x.u = ((unsigned)b) << 16;
    return x.f;
}
static __device__ __forceinline__ float bflo(unsigned v) {
    union { unsigned u; float f; } x; x.u = v << 16;
    return x.f;
}
static __device__ __forceinline__ float bfhi(unsigned v) {
    union { unsigned u; float f; } x; x.u = v & 0xFFFF0000u;
    return x.f;
}
static __device__ __forceinline__ bool bit_test(const unsigned* __restrict__ bm, int i) {
    return (bm[i >> 5] >> (i & 31)) & 1u;
}

// dedup-append node s to frontier list; set bits in bmCur and bmL
static __device__ __forceinline__ void try_append(int s, int* __restrict__ pos,
                                                  int* __restrict__ list, int* __restrict__ cnt,
                                                  unsigned* __restrict__ bmCur,
                                                  unsigned* __restrict__ bmL) {
    if (atomicCAS(&pos[s], -1, -2) == -1) {
        int i = atomicAdd(cnt, 1);
        list[i] = s;
        atomicOr(&bmCur[s >> 5], 1u << (s & 31));
        atomicOr(&bmL[s >> 5], 1u << (s & 31));
        atomicExch(&pos[s], i);
    }
}

// ---- pass 1 (+ fused weight split): edges into claim -> B0; srcs -> S1 ----
__global__ void k_pass1(const int* __restrict__ src, const int* __restrict__ dst,
                        const int* __restrict__ claim, int* __restrict__ B0,
                        int* __restrict__ cur0, int* __restrict__ pos1,
                        int* __restrict__ list1, int* __restrict__ cnt1,
                        unsigned* __restrict__ bm1, unsigned* __restrict__ bmL,
                        const float* __restrict__ W_in, const float* __restrict__ W_gnn,
                        unsigned short* __restrict__ Wth_in, unsigned short* __restrict__ Wtl_in,
                        unsigned short* __restrict__ Wth_g, unsigned short* __restrict__ Wtl_g,
                        int E) {
    int idx = blockIdx.x * 256 + threadIdx.x;
    int nth = gridDim.x * 256;
    // fused weight convert+transpose+split (independent of edge work)
    {
        const int n1 = D_IN * H_DIM;
        const int ntot = n1 + 2 * H_DIM * H_DIM;
        for (int id = idx; id < ntot; id += nth) {
            if (id < n1) {
                int k = id >> 8, n = id & 255;
                float w = W_in[id];
                unsigned short h = f2bf(w);
                Wth_in[(size_t)n * D_IN + k] = h;
                Wtl_in[(size_t)n * D_IN + k] = f2bf(w - bf2f(h));
            } else {
                int t = id - n1;
                int l = t >> 16, r = t & 65535;
                int k = r >> 8, n = r & 255;
                float w = W_gnn[(size_t)l * 65536 + r];
                unsigned short h = f2bf(w);
                Wth_g[(size_t)l * 65536 + (size_t)n * H_DIM + k] = h;
                Wtl_g[(size_t)l * 65536 + (size_t)n * H_DIM + k] = f2bf(w - bf2f(h));
            }
        }
    }
    int c = claim[0];
    int e0 = idx * 8;
    if (e0 >= E) return;
    if (e0 + 8 <= E) {
        int4 da = *(const int4*)(dst + e0);
        int4 db = *(const int4*)(dst + e0 + 4);
        int ds[8] = {da.x, da.y, da.z, da.w, db.x, db.y, db.z, db.w};
#pragma unroll
        for (int k = 0; k < 8; k++) {
            if (ds[k] == c) {
                int s = src[e0 + k];
                int p = atomicAdd(cur0, 1);
                if (p < CAP0) B0[p] = s;
                try_append(s, pos1, list1, cnt1, bm1, bmL);
            }
        }
    } else {
        for (int e = e0; e < E; e++) {
            if (dst[e] == c) {
                int s = src[e];
                int p = atomicAdd(cur0, 1);
                if (p < CAP0) B0[p] = s;
                try_append(s, pos1, list1, cnt1, bm1, bmL);
            }
        }
    }
}

// ---- fused scan+expand: phase A (branchless) match byte -> LDS; phase B
// (wave 0, post-barrier) expands the block's sparse matches. ----
__global__ void k_scan_expand(const int* __restrict__ src, const int* __restrict__ dst,
                              const unsigned* __restrict__ bmPrev, const int* __restrict__ posPrev,
                              int* __restrict__ bucket, int* __restrict__ cur,
                              int* __restrict__ posCur, int* __restrict__ listCur,
                              int* __restrict__ cntCur,
                              unsigned* __restrict__ bmCur, unsigned* __restrict__ bmL, int E) {
    __shared__ unsigned mwords[64];          // 256 match bytes
    int tid = threadIdx.x;
    int e0 = blockIdx.x * 2048 + tid * 8;
    unsigned m = 0;
    if (e0 + 8 <= E) {
        int4 da = *(const int4*)(dst + e0);
        int4 db = *(const int4*)(dst + e0 + 4);
        m  = bit_test(bmPrev, da.x) ? 1u : 0u;
        m |= bit_test(bmPrev, da.y) ? 2u : 0u;
        m |= bit_test(bmPrev, da.z) ? 4u : 0u;
        m |= bit_test(bmPrev, da.w) ? 8u : 0u;
        m |= bit_test(bmPrev, db.x) ? 16u : 0u;
        m |= bit_test(bmPrev, db.y) ? 32u : 0u;
        m |= bit_test(bmPrev, db.z) ? 64u : 0u;
        m |= bit_test(bmPrev, db.w) ? 128u : 0u;
    } else {
        for (int e = e0; e < E; e++)
            if (bit_test(bmPrev, dst[e])) m |= 1u << (e - e0);
    }
    ((unsigned char*)mwords)[tid] = (unsigned char)m;
    __syncthreads();
    if (tid >= 64) return;                    // waves 1-3 done
    unsigned w = mwords[tid];                 // word = threads 4t..4t+3
    int base = blockIdx.x * 2048 + tid * 32;  // 4 threads x 8 edges
    while (w) {
        int b = __ffs(w) - 1;
        w &= w - 1;
        int e = base + (b >> 3) * 8 + (b & 7);
        int s = src[e], d = dst[e];
        int pt = posPrev[d];
        int p = atomicAdd(&cur[pt], 1);
        if (p < CAPDEG) bucket[(size_t)pt * CAPDEG + p] = s;
        try_append(s, posCur, listCur, cntCur, bmCur, bmL);
    }
}

// ---- out-degrees for live nodes (predicated void atomics; proven-fast shape) ----
__global__ void k_deg(const int* __restrict__ src, const unsigned* __restrict__ bmL,
                      int* __restrict__ deg_out, int E) {
    int idx = blockIdx.x * 256 + threadIdx.x;
    int e0 = idx * 8;
    if (e0 >= E) return;
    if (e0 + 8 <= E) {
        int4 a = *(const int4*)(src + e0);
        int4 b = *(const int4*)(src + e0 + 4);
        int ss[8] = {a.x, a.y, a.z, a.w, b.x, b.y, b.z, b.w};
#pragma unroll
        for (int k = 0; k < 8; k++)
            if (bit_test(bmL, ss[k])) atomicAdd(&deg_out[ss[k]], 1);
    } else {
        for (int e = e0; e < E; e++) {
            int s = src[e];
            if (bit_test(bmL, s)) atomicAdd(&deg_out[s], 1);
        }
    }
}

// ---- split-precision MFMA GEMM, BM=64 x BN=256 (full width, single col block;
// each A row fetched exactly once). 4 waves; wave wv owns 64 rows x cols
// [wv*64, wv*64+64). Passes: Ah*Bh always; + Al*Bh if ALO; + Ah*Bl if BLO.
// Msg[row][256] = (relu?)(acc+bias) * rsqrt(deg_out[rowmap[row]])  (bf16)
template<bool GATHER_A, bool RELU, bool ALO, bool BLO>
__global__ __launch_bounds__(256) void k_mfma_gemm(
    const float* __restrict__ A, const int* __restrict__ rowmap,
    const int* __restrict__ Mptr,
    const unsigned short* __restrict__ Bth, const unsigned short* __restrict__ Btl,
    const float* __restrict__ bias, const int* __restrict__ deg_out,
    unsigned short* __restrict__ MsgOut, int K) {
    int M = Mptr[0];
    int row0 = blockIdx.x * 64;
    if (row0 >= M) return;

    __shared__ unsigned short Ash[64][40];
    __shared__ unsigned short Asl[ALO ? 64 : 1][40];
    __shared__ unsigned short Bsh[256][40];
    __shared__ unsigned short Bsl[BLO ? 256 : 1][40];

    int tid = threadIdx.x;
    int lane = tid & 63;
    int wv = tid >> 6;          // wave's 64-col quarter

    f32x4 acc[4][4];
#pragma unroll
    for (int mi = 0; mi < 4; mi++)
#pragma unroll
        for (int ni = 0; ni < 4; ni++) acc[mi][ni] = (f32x4){0.f, 0.f, 0.f, 0.f};

    int kf = (lane >> 4) * 8;
    int rsel = lane & 15;

    for (int kk = 0; kk < K; kk += 32) {
        // stage A: 64 rows x 32 cols fp32 = 512 float4, 2 per thread
#pragma unroll
        for (int u = 0; u < 2; u++) {
            int i = tid + u * 256;
            int r = i >> 3;
            int c4 = (i & 7) * 4;
            float4 v = {0.f, 0.f, 0.f, 0.f};
            int row = row0 + r;
            if (row < M) {
                int arow = GATHER_A ? rowmap[row] : row;
                v = *(const float4*)(A + (size_t)arow * K + kk + c4);
            }
            ushort4 h;
            h.x = f2bf(v.x); h.y = f2bf(v.y); h.z = f2bf(v.z); h.w = f2bf(v.w);
            *(ushort4*)&Ash[r][c4] = h;
            if (ALO) {
                ushort4 l;
                l.x = f2bf(v.x - bf2f(h.x));
                l.y = f2bf(v.y - bf2f(h.y));
                l.z = f2bf(v.z - bf2f(h.z));
                l.w = f2bf(v.w - bf2f(h.w));
                *(ushort4*)&Asl[r][c4] = l;
            }
        }
        // stage B: 256 n-rows x 32 k = 1024 uint4, 4 per thread per buffer
#pragma unroll
        for (int u = 0; u < 4; u++) {
            int i = tid + u * 256;
            int r = i >> 2;
            int c8 = (i & 3) * 8;
            *(uint4*)&Bsh[r][c8] = *(const uint4*)(Bth + (size_t)r * K + kk + c8);
            if (BLO)
                *(uint4*)&Bsl[r][c8] = *(const uint4*)(Btl + (size_t)r * K + kk + c8);
        }
        __syncthreads();

        bf16x8 ah[4], al[4], bh[4], bl[4];
#pragma unroll
        for (int mi = 0; mi < 4; mi++) {
            ah[mi] = *(const bf16x8*)&Ash[mi * 16 + rsel][kf];
            if (ALO) al[mi] = *(const bf16x8*)&Asl[mi * 16 + rsel][kf];
        }
#pragma unroll
        for (int ni = 0; ni < 4; ni++) {
            bh[ni] = *(const bf16x8*)&Bsh[wv * 64 + ni * 16 + rsel][kf];
            if (BLO) bl[ni] = *(const bf16x8*)&Bsl[wv * 64 + ni * 16 + rsel][kf];
        }
#pragma unroll
        for (int mi = 0; mi < 4; mi++)
#pragma unroll
            for (int ni = 0; ni < 4; ni++) {
                acc[mi][ni] = __builtin_amdgcn_mfma_f32_16x16x32_bf16(ah[mi], bh[ni], acc[mi][ni], 0, 0, 0);
                if (ALO)
                    acc[mi][ni] = __builtin_amdgcn_mfma_f32_16x16x32_bf16(al[mi], bh[ni], acc[mi][ni], 0, 0, 0);
                if (BLO)
                    acc[mi][ni] = __builtin_amdgcn_mfma_f32_16x16x32_bf16(ah[mi], bl[ni], acc[mi][ni], 0, 0, 0);
            }
        __syncthreads();
    }

    int lr = (lane >> 4) * 4;
    int lc = lane & 15;
    float bcol[4];
#pragma unroll
    for (int ni = 0; ni < 4; ni++) bcol[ni] = bias[wv * 64 + ni * 16 + lc];

#pragma unroll
    for (int mi = 0; mi < 4; mi++) {
#pragma unroll
        for (int r = 0; r < 4; r++) {
            int row = row0 + mi * 16 + lr + r;
            if (row >= M) continue;
            float ns = rsqrtf((float)max(deg_out[rowmap[row]], 1));
#pragma unroll
            for (int ni = 0; ni < 4; ni++) {
                int col = wv * 64 + ni * 16 + lc;
                float v = acc[mi][ni][r] + bcol[ni];
                if (RELU) v = fmaxf(v, 0.f);
                MsgOut[(size_t)row * 256 + col] = f2bf(v * ns);
            }
        }
    }
}

// ---- bucket aggregation: one wave per target; norm_dst from bucket cursor ----
__global__ void k_gather_agg(const int* __restrict__ nTptr, const int* __restrict__ bucket,
                             const int* __restrict__ cur, const int* __restrict__ posSrc,
                             const uint2* __restrict__ Msg, float4* __restrict__ Agg) {
    int nT = nTptr[0];
    int gt = blockIdx.x * blockDim.x + threadIdx.x;
    int w = gt >> 6, lane = gt & 63;
    if (w >= nT) return;
    int deg = cur[w];
    int ne = min(deg, CAPDEG);
    const int* bk = bucket + (size_t)w * CAPDEG;
    float a0 = 0.f, a1 = 0.f, a2 = 0.f, a3 = 0.f;
    int e = 0;
    for (; e + 1 < ne; e += 2) {
        int s0 = __builtin_amdgcn_readfirstlane(bk[e]);
        int s1 = __builtin_amdgcn_readfirstlane(bk[e + 1]);
        int i0 = __builtin_amdgcn_readfirstlane(posSrc[s0]);
        int i1 = __builtin_amdgcn_readfirstlane(posSrc[s1]);
        uint2 v0 = Msg[(size_t)i0 * 64 + lane];
        uint2 v1 = Msg[(size_t)i1 * 64 + lane];
        a0 += bflo(v0.x) + bflo(v1.x);
        a1 += bfhi(v0.x) + bfhi(v1.x);
        a2 += bflo(v0.y) + bflo(v1.y);
        a3 += bfhi(v0.y) + bfhi(v1.y);
    }
    for (; e < ne; e++) {
        int s = __builtin_amdgcn_readfirstlane(bk[e]);
        int i0 = __builtin_amdgcn_readfirstlane(posSrc[s]);
        uint2 v = Msg[(size_t)i0 * 64 + lane];
        a0 += bflo(v.x); a1 += bfhi(v.x); a2 += bflo(v.y); a3 += bfhi(v.y);
    }
    float nd = rsqrtf((float)max(deg, 1));
    float4 o;
    o.x = a0 * nd; o.y = a1 * nd; o.z = a2 * nd; o.w = a3 * nd;
    Agg[(size_t)w * 64 + lane] = o;
}

// ---- final: claim aggregation (bucket B0) + layer-3 GEMV + classifier head ----
__global__ void k_final(const int* __restrict__ B0, const int* __restrict__ cur0,
                        const int* __restrict__ pos1, const unsigned short* __restrict__ Msg2,
                        const float* __restrict__ W3, const float* __restrict__ b3,
                        const float* __restrict__ Wc1, const float* __restrict__ bc1,
                        const float* __restrict__ Wc2, const float* __restrict__ bc2,
                        float* __restrict__ out) {
    __shared__ float agg[H_DIM];
    __shared__ float h3[H_DIM];
    __shared__ float hid[H_HALF];
    int t = threadIdx.x;
    int deg = cur0[0];
    int ne = min(deg, CAP0);
    float a = 0.f;
    for (int e = 0; e < ne; e++) {
        int s = B0[e];
        int idx = pos1[s];
        a += bf2f(Msg2[(size_t)idx * H_DIM + t]);
    }
    agg[t] = a * rsqrtf((float)max(deg, 1));
    __syncthreads();
    float acc = b3[t];
    for (int k = 0; k < H_DIM; k++) acc += agg[k] * W3[k * H_DIM + t];
    h3[t] = fmaxf(acc, 0.f);
    __syncthreads();
    if (t < H_HALF) {
        float x = bc1[t];
        for (int k = 0; k < H_DIM; k++) x += h3[k] * Wc1[k * H_HALF + t];
        hid[t] = fmaxf(x, 0.f);
    }
    __syncthreads();
    if (t < N_CLASSES) {
        float x = bc2[t];
        for (int j = 0; j < H_HALF; j++) x += hid[j] * Wc2[j * N_CLASSES + t];
        out[t] = x;
    }
}

extern "C" void kernel_launch(void* const* d_in, const int* in_sizes, int n_in,
                              void* d_out, int out_size, void* d_ws, size_t ws_size,
                              hipStream_t stream) {
    const float* nf    = (const float*)d_in[0];
    const int*   esrc  = (const int*)d_in[1];
    const int*   edst  = (const int*)d_in[2];
    const int*   claim = (const int*)d_in[3];
    const float* W_in  = (const float*)d_in[4];
    const float* b_in  = (const float*)d_in[5];
    const float* W_gnn = (const float*)d_in[6];
    const float* b_gnn = (const float*)d_in[7];
    const float* Wc1   = (const float*)d_in[8];
    const float* bc1   = (const float*)d_in[9];
    const float* Wc2   = (const float*)d_in[10];
    const float* bc2   = (const float*)d_in[11];

    const int N = in_sizes[0] / D_IN;
    const int E = in_sizes[1];
    const int BMWP = (((N + 31) / 32) + 63) & ~63;   // bitmap words, 256B-aligned stride

    char* p = (char*)d_ws;
    auto alloc = [&](size_t bytes) -> void* {
        void* r = (void*)p;
        p += (bytes + 255) & ~(size_t)255;
        return r;
    };
    // ---- zero region (single memset) ----
    char* zero0 = p;
    int* deg_out  = (int*)alloc((size_t)N * 4);
    unsigned* bms = (unsigned*)alloc((size_t)3 * BMWP * 4);  // bm1 | bm2 | bmL
    int* cnt      = (int*)alloc(8 * 4);      // [c1, c2, c3, cur0]
    int* cur1     = (int*)alloc((size_t)CAP1 * 4);
    int* cur2     = (int*)alloc((size_t)CAP2 * 4);
    size_t zeroBytes = (size_t)(p - zero0);
    // ---- 0xFF region (single memset) ----
    char* ff0 = p;
    int* pos1     = (int*)alloc((size_t)N * 4);
    int* pos2     = (int*)alloc((size_t)N * 4);
    int* pos3     = (int*)alloc((size_t)N * 4);
    size_t ffBytes = (size_t)(p - ff0);
    // ---- uninitialized ----
    unsigned* bm1 = bms;
    unsigned* bm2 = bms + BMWP;
    unsigned* bmL = bms + 2 * BMWP;
    int* list1    = (int*)alloc((size_t)CAP1 * 4);
    int* list2    = (int*)alloc((size_t)CAP2 * 4);
    int* list3    = (int*)alloc((size_t)N * 4);
    int* B0       = (int*)alloc((size_t)CAP0 * 4);
    int* B1       = (int*)alloc((size_t)CAP1 * CAPDEG * 4);
    int* B2       = (int*)alloc((size_t)CAP2 * CAPDEG * 4);
    unsigned short* Wth_in = (unsigned short*)alloc((size_t)D_IN * H_DIM * 2);
    unsigned short* Wtl_in = (unsigned short*)alloc((size_t)D_IN * H_DIM * 2);
    unsigned short* Wth_g  = (unsigned short*)alloc((size_t)2 * H_DIM * H_DIM * 2);
    unsigned short* Wtl_g  = (unsigned short*)alloc((size_t)2 * H_DIM * H_DIM * 2);
    unsigned short* Msg0 = (unsigned short*)alloc((size_t)N * H_DIM * 2);
    unsigned short* Msg1 = (unsigned short*)alloc((size_t)CAP2 * H_DIM * 2);
    unsigned short* Msg2 = (unsigned short*)alloc((size_t)CAP1 * H_DIM * 2);
    float* Agg1 = (float*)alloc((size_t)CAP2 * H_DIM * 4);
    float* Agg2 = (float*)alloc((size_t)CAP1 * H_DIM * 4);

    hipMemsetAsync(zero0, 0, zeroBytes, stream);
    hipMemsetAsync(ff0, 0xFF, ffBytes, stream);

    int e8b = (E + 2047) / 2048;   // 8 edges/thread, 256 threads/block

    // level 1: direct in-neighbors of claim (+ fused weight split)
    k_pass1<<<e8b, 256, 0, stream>>>(esrc, edst, claim, B0, cnt + 3, pos1, list1, cnt,
                                     bm1, bmL, W_in, W_gnn, Wth_in, Wtl_in, Wth_g, Wtl_g, E);
    // level 2: fused branchless scan + sparse expand
    k_scan_expand<<<e8b, 256, 0, stream>>>(esrc, edst, bm1, pos1, B1, cur1,
                                           pos2, list2, cnt + 1, bm2, bmL, E);
    // level 3: fused branchless scan + sparse expand
    k_scan_expand<<<e8b, 256, 0, stream>>>(esrc, edst, bm2, pos2, B2, cur2,
                                           pos3, list3, cnt + 2, bmL, bmL, E);
    // out-degrees of live nodes
    k_deg<<<e8b, 256, 0, stream>>>(esrc, bmL, deg_out, E);

    // projection on S3 (single-pass bf16, 64x256 tile, A read once)
    k_mfma_gemm<true, false, false, false><<<(N + 63) / 64, 256, 0, stream>>>(
        nf, list3, cnt + 2, Wth_in, Wtl_in, b_in, deg_out, Msg0, D_IN);

    // layer 1: aggregate S2 targets from Msg0, then GEMM (full split)
    k_gather_agg<<<(CAP2 * 64 + 255) / 256, 256, 0, stream>>>(cnt + 1, B2, cur2, pos3,
                                                              (const uint2*)Msg0, (float4*)Agg1);
    k_mfma_gemm<false, true, true, true><<<CAP2 / 64, 256, 0, stream>>>(
        Agg1, list2, cnt + 1, Wth_g, Wtl_g, b_gnn, deg_out, Msg1, H_DIM);

    // layer 2: aggregate S1 targets from Msg1, then GEMM (full split)
    k_gather_agg<<<(CAP1 * 64 + 255) / 256, 256, 0, stream>>>(cnt, B1, cur1, pos2,
                                                              (const uint2*)Msg1, (float4*)Agg2);
    k_mfma_gemm<false, true, true, true><<<CAP1 / 64, 256, 0, stream>>>(
        Agg2, list1, cnt, Wth_g + (size_t)H_DIM * H_DIM, Wtl_g + (size_t)H_DIM * H_DIM,
        b_gnn + H_DIM, deg_out, Msg2, H_DIM);

    // layer 3 (claim only) + classifier head
    k_final<<<1, H_DIM, 0, stream>>>(B0, cnt + 3, pos1, Msg2,
                                     W_gnn + (size_t)2 * H_DIM * H_DIM, b_gnn + 2 * H_DIM,
                                     Wc1, bc1, Wc2, bc2, (float*)d_out);
}